// Round 1
// baseline (8149.917 us; speedup 1.0000x reference)
//
#include <hip/hip_runtime.h>
#include <math.h>

typedef float f4 __attribute__((ext_vector_type(4)));
typedef float f2 __attribute__((ext_vector_type(2)));

#define NT 256

__global__ __launch_bounds__(NT, 2)
void img2svg_fused(const float* __restrict__ data,
                   const float* __restrict__ w1, const float* __restrict__ b1,
                   const float* __restrict__ w2, const float* __restrict__ b2,
                   const float* __restrict__ w3, const float* __restrict__ b3,
                   const float* __restrict__ w4, const float* __restrict__ b4,
                   const float* __restrict__ wd1, const float* __restrict__ bd1,
                   const float* __restrict__ wd2, const float* __restrict__ bd2,
                   float* __restrict__ out)
{
    __shared__ float s_in[144];          // 12x12 zero-padded input
    __shared__ float s_w1[1152];
    __shared__ float s_act1[101 * 128];  // conv1 out 10x10x128 + zero row (idx 100)
    __shared__ float s_p2[26 * 128];     // pooled conv2 5x5x128 + zero row (idx 25)
    __shared__ float s_act3[26 * 64];    // conv3 out 5x5x64 + zero row (idx 25)
    __shared__ float s_pool4[4 * 64];    // pooled conv4 2x2x64 (atomicMax targets)
    __shared__ float s_feat[64];
    __shared__ float s_h[32];

    const int t = threadIdx.x;
    const int img = blockIdx.x;

    // ---------------- P0: stage input, w1, zero-fill special rows ----------------
    if (t < 144) {
        int r = t / 12, c = t % 12;
        float v = 0.f;
        if (r >= 1 && r <= 10 && c >= 1 && c <= 10)
            v = data[img * 100 + (r - 1) * 10 + (c - 1)];
        s_in[t] = v;
    }
    for (int i = t; i < 1152; i += NT) s_w1[i] = w1[i];
    if (t < 128) s_act1[12800 + t] = 0.f;   // zero row for conv2 OOB reads
    s_p2[3072 + t] = 0.f;                   // cell-24 slots (atomic) + zero row 25
    if (t < 64) s_act3[1600 + t] = 0.f;     // zero row for conv4 OOB reads
    s_pool4[t] = 0.f;
    __syncthreads();

    // ---------------- P1: conv1 (1->128, 3x3 SAME, relu) ----------------
    for (int k = 0; k < 50; ++k) {
        int o = t + k * NT;          // 0..12799
        int p = o >> 7, c = o & 127;
        int y = p / 10, x = p - 10 * y;
        float acc = b1[c];
#pragma unroll
        for (int tap = 0; tap < 9; ++tap) {
            int dy = tap / 3, dx = tap % 3;
            acc = fmaf(s_in[(y + dy) * 12 + (x + dx)], s_w1[tap * 128 + c], acc);
        }
        s_act1[p * 128 + c] = fmaxf(acc, 0.f);
    }
    __syncthreads();

    // ---------------- P2: conv2 (128->128, 3x3 SAME, relu) + 2x2 maxpool ----------------
    {
        const int cog = t & 31;          // 4 consecutive out-channels
        const int co4 = cog << 2;
        const int cellg = t >> 5;        // 0..7, owns pool cells {g, g+8, g+16}
        const bool hasx = (cellg < 4);   // groups 0..3 also own one sub-pos of cell 24
        const int xsy = cellg >> 1, xsx = cellg & 1;

        int cyA[3], cxA[3];
#pragma unroll
        for (int n = 0; n < 3; ++n) {
            int cell = cellg + 8 * n;
            cyA[n] = cell / 5;
            cxA[n] = cell - 5 * cyA[n];
        }

        float acc[3][4][4];
        float acc4[4];
#pragma unroll
        for (int i = 0; i < 4; ++i) {
            float bi = b2[co4 + i];
#pragma unroll
            for (int n = 0; n < 3; ++n)
#pragma unroll
                for (int s2 = 0; s2 < 4; ++s2) acc[n][s2][i] = bi;
            acc4[i] = bi;
        }

        const f4* w2v = (const f4*)w2;

        for (int tap = 0; tap < 9; ++tap) {
            int dy = tap / 3, dx = tap - 3 * (tap / 3);
            int q[3][4], qx;
#pragma unroll
            for (int n = 0; n < 3; ++n)
#pragma unroll
                for (int s2 = 0; s2 < 4; ++s2) {
                    int ay = 2 * cyA[n] + (s2 >> 1) + dy - 1;
                    int ax = 2 * cxA[n] + (s2 & 1) + dx - 1;
                    q[n][s2] = ((unsigned)ay < 10u && (unsigned)ax < 10u)
                                   ? ((ay * 10 + ax) << 7) : 12800;
                }
            {
                int ay = 8 + xsy + dy - 1;
                int ax = 8 + xsx + dx - 1;
                qx = ((unsigned)ay < 10u && (unsigned)ax < 10u)
                         ? ((ay * 10 + ax) << 7) : 12800;
            }

            for (int ci = 0; ci < 128; ci += 4) {
                f4 av[3][4], avx;
#pragma unroll
                for (int n = 0; n < 3; ++n)
#pragma unroll
                    for (int s2 = 0; s2 < 4; ++s2)
                        av[n][s2] = *(const f4*)&s_act1[q[n][s2] + ci];
                if (hasx) avx = *(const f4*)&s_act1[qx + ci];

#pragma unroll
                for (int u = 0; u < 4; ++u) {
                    f4 w = w2v[((tap << 7) + ci + u) * 32 + cog];
#pragma unroll
                    for (int n = 0; n < 3; ++n)
#pragma unroll
                        for (int s2 = 0; s2 < 4; ++s2) {
                            float a = av[n][s2][u];
#pragma unroll
                            for (int i = 0; i < 4; ++i)
                                acc[n][s2][i] = fmaf(a, w[i], acc[n][s2][i]);
                        }
                    if (hasx) {
                        float a = avx[u];
#pragma unroll
                        for (int i = 0; i < 4; ++i)
                            acc4[i] = fmaf(a, w[i], acc4[i]);
                    }
                }
            }
        }

        // relu + 2x2 maxpool -> s_p2
#pragma unroll
        for (int n = 0; n < 3; ++n) {
            int cell = cellg + 8 * n;
#pragma unroll
            for (int i = 0; i < 4; ++i) {
                float m = fmaxf(fmaxf(acc[n][0][i], acc[n][1][i]),
                                fmaxf(acc[n][2][i], acc[n][3][i]));
                m = fmaxf(m, 0.f);
                s_p2[cell * 128 + co4 + i] = m;
            }
        }
        if (hasx) {
#pragma unroll
            for (int i = 0; i < 4; ++i) {
                float r = fmaxf(acc4[i], 0.f);
                atomicMax((int*)&s_p2[24 * 128 + co4 + i], __float_as_int(r));
            }
        }
    }
    __syncthreads();

    // ---------------- P3: conv3 (128->64, 3x3 SAME, relu) ----------------
    {
        const int cog = t & 15;
        const int co4 = cog << 2;
        const int pg = t >> 4;          // 0..15
        const int p0 = pg, p1 = pg + 16;
        const bool has1 = (p1 < 25);
        const int py0 = p0 / 5, px0 = p0 - 5 * py0;
        const int py1 = p1 / 5, px1 = p1 - 5 * py1;

        float acc[2][4];
#pragma unroll
        for (int i = 0; i < 4; ++i) { float bi = b3[co4 + i]; acc[0][i] = bi; acc[1][i] = bi; }

        const f4* w3v = (const f4*)w3;

        for (int tap = 0; tap < 9; ++tap) {
            int dy = tap / 3, dx = tap - 3 * (tap / 3);
            int ay0 = py0 + dy - 1, ax0 = px0 + dx - 1;
            int ay1 = py1 + dy - 1, ax1 = px1 + dx - 1;
            int q0 = ((unsigned)ay0 < 5u && (unsigned)ax0 < 5u) ? ((ay0 * 5 + ax0) << 7) : 3200;
            int q1 = ((unsigned)ay1 < 5u && (unsigned)ax1 < 5u) ? ((ay1 * 5 + ax1) << 7) : 3200;

            for (int ci = 0; ci < 128; ci += 4) {
                f4 a0 = *(const f4*)&s_p2[q0 + ci];
                f4 a1 = *(const f4*)&s_p2[q1 + ci];
#pragma unroll
                for (int u = 0; u < 4; ++u) {
                    f4 w = w3v[((tap << 7) + ci + u) * 16 + cog];
#pragma unroll
                    for (int i = 0; i < 4; ++i) {
                        acc[0][i] = fmaf(a0[u], w[i], acc[0][i]);
                        acc[1][i] = fmaf(a1[u], w[i], acc[1][i]);
                    }
                }
            }
        }
#pragma unroll
        for (int i = 0; i < 4; ++i) s_act3[p0 * 64 + co4 + i] = fmaxf(acc[0][i], 0.f);
        if (has1) {
#pragma unroll
            for (int i = 0; i < 4; ++i) s_act3[p1 * 64 + co4 + i] = fmaxf(acc[1][i], 0.f);
        }
    }
    __syncthreads();

    // ---------------- P4: conv4 (64->64, 3x3 SAME, relu) + 2x2 maxpool (4x4 region) ----------------
    {
        const int cog = t & 31;          // 2 consecutive out-channels
        const int co2 = cog << 1;
        const int pg = t >> 5;           // 0..7 -> positions pg, pg+8 in the 4x4 grid
        const int pA = pg, pB = pg + 8;
        const int ry0 = pA >> 2, rx0 = pA & 3;
        const int ry1 = pB >> 2, rx1 = pB & 3;

        float acc[2][2];
#pragma unroll
        for (int i = 0; i < 2; ++i) { float bi = b4[co2 + i]; acc[0][i] = bi; acc[1][i] = bi; }

        const f2* w4v = (const f2*)w4;

        for (int tap = 0; tap < 9; ++tap) {
            int dy = tap / 3, dx = tap - 3 * (tap / 3);
            int ay0 = ry0 + dy - 1, ax0 = rx0 + dx - 1;
            int ay1 = ry1 + dy - 1, ax1 = rx1 + dx - 1;
            int q0 = ((unsigned)ay0 < 5u && (unsigned)ax0 < 5u) ? ((ay0 * 5 + ax0) << 6) : 1600;
            int q1 = ((unsigned)ay1 < 5u && (unsigned)ax1 < 5u) ? ((ay1 * 5 + ax1) << 6) : 1600;

            for (int ci = 0; ci < 64; ci += 4) {
                f4 a0 = *(const f4*)&s_act3[q0 + ci];
                f4 a1 = *(const f4*)&s_act3[q1 + ci];
#pragma unroll
                for (int u = 0; u < 4; ++u) {
                    f2 w = w4v[((tap << 6) + ci + u) * 32 + cog];
#pragma unroll
                    for (int i = 0; i < 2; ++i) {
                        acc[0][i] = fmaf(a0[u], w[i], acc[0][i]);
                        acc[1][i] = fmaf(a1[u], w[i], acc[1][i]);
                    }
                }
            }
        }
        // relu + atomic max-pool into 2x2 cells
        const int cell0 = (ry0 >> 1) * 2 + (rx0 >> 1);
        const int cell1 = (ry1 >> 1) * 2 + (rx1 >> 1);
#pragma unroll
        for (int i = 0; i < 2; ++i) {
            float r0 = fmaxf(acc[0][i], 0.f);
            float r1 = fmaxf(acc[1][i], 0.f);
            atomicMax((int*)&s_pool4[cell0 * 64 + co2 + i], __float_as_int(r0));
            atomicMax((int*)&s_pool4[cell1 * 64 + co2 + i], __float_as_int(r1));
        }
    }
    __syncthreads();

    // ---------------- P5: mean + dense1 ----------------
    if (t < 64) {
        float f = 0.25f * (s_pool4[t] + s_pool4[64 + t] + s_pool4[128 + t] + s_pool4[192 + t]);
        s_feat[t] = f;
    }
    __syncthreads();
    if (t < 32) {
        float h = bd1[t];
        for (int i = 0; i < 64; ++i) h = fmaf(s_feat[i], wd1[i * 32 + t], h);
        s_h[t] = fmaxf(h, 0.f);
    }
    __syncthreads();

    // ---------------- P6: dense2 + sigmoid + bezier + round + sort + dedup ----------------
    if (t == 0) {
        float v[4];
#pragma unroll
        for (int o = 0; o < 4; ++o) {
            float vv = bd2[o];
            for (int i = 0; i < 32; ++i) vv = fmaf(s_h[i], wd2[i * 4 + o], vv);
            v[o] = 1.f / (1.f + expf(-vv));
        }
        float px[5], py[5], pp[5];
#pragma unroll
        for (int k = 0; k < 5; ++k) {
            float tk = 0.25f * (float)k;
            float gx = ((1.f - tk) * v[0] + tk * v[2]) * 10.f;
            float gy = ((1.f - tk) * v[1] + tk * v[3]) * 10.f;
            px[k] = rintf(gx);           // round half-to-even, matches np.round
            py[k] = rintf(gy);
            pp[k] = px[k] * 10.f + py[k];
        }
        // stable bubble sort ascending by pp (strict > swap => stable like argsort stable)
#pragma unroll
        for (int pass = 0; pass < 4; ++pass)
#pragma unroll
            for (int i = 0; i < 4 - pass; ++i) {
                bool sw = pp[i] > pp[i + 1];
                float a, b;
                a = pp[i]; b = pp[i + 1]; pp[i] = sw ? b : a; pp[i + 1] = sw ? a : b;
                a = px[i]; b = px[i + 1]; px[i] = sw ? b : a; px[i + 1] = sw ? a : b;
                a = py[i]; b = py[i + 1]; py[i] = sw ? b : a; py[i + 1] = sw ? a : b;
            }
        float* op = out + img * 10;
#pragma unroll
        for (int i = 0; i < 5; ++i) { op[2 * i] = -1.f; op[2 * i + 1] = -1.f; }
        int k2 = 0;
#pragma unroll
        for (int i = 0; i < 5; ++i) {
            bool keep;
            if (i == 0) keep = true;
            else keep = (fabsf(px[i] - px[i - 1]) + fabsf(py[i] - py[i - 1])) != 0.f;
            if (keep) {
                op[2 * k2] = px[i];
                op[2 * k2 + 1] = py[i];
                ++k2;
            }
        }
    }
}

extern "C" void kernel_launch(void* const* d_in, const int* in_sizes, int n_in,
                              void* d_out, int out_size, void* d_ws, size_t ws_size,
                              hipStream_t stream) {
    const float* data = (const float*)d_in[0];
    const float* w1  = (const float*)d_in[1];
    const float* b1  = (const float*)d_in[2];
    const float* w2  = (const float*)d_in[3];
    const float* b2  = (const float*)d_in[4];
    const float* w3  = (const float*)d_in[5];
    const float* b3  = (const float*)d_in[6];
    const float* w4  = (const float*)d_in[7];
    const float* b4  = (const float*)d_in[8];
    const float* wd1 = (const float*)d_in[9];
    const float* bd1 = (const float*)d_in[10];
    const float* wd2 = (const float*)d_in[11];
    const float* bd2 = (const float*)d_in[12];
    float* out = (float*)d_out;

    int nimg = in_sizes[0] / 100;
    img2svg_fused<<<nimg, NT, 0, stream>>>(data, w1, b1, w2, b2, w3, b3, w4, b4,
                                           wd1, bd1, wd2, bd2, out);
}

// Round 2
// 1887.581 us; speedup vs baseline: 4.3177x; 4.3177x over previous
//
#include <hip/hip_runtime.h>
#include <hip/hip_bf16.h>
#include <math.h>

typedef float f4 __attribute__((ext_vector_type(4)));
typedef float f32x4 __attribute__((ext_vector_type(4)));
typedef __bf16 bf16x8 __attribute__((ext_vector_type(8)));
typedef unsigned int uint32x4 __attribute__((ext_vector_type(4)));

#define NT 256

// ---------------------------------------------------------------------------
// Weight repack: w2 (3,3,128,128) and w3 (3,3,128,64) f32 -> bf16 in MFMA
// B-fragment order.  B-frag for 16x16x32: lane l holds B[k = kg*8+j][co = l&15],
// kg = l>>4.  Layout: pk[(tap*4+cs)][ntile][lane][j]  (8 bf16 = 16B per lane).
// pk2: 9*4*8*64*8 bf16 = 294912 B at ws+0
// pk3: 9*4*4*64*8 bf16 = 147456 B at ws+294912
// ---------------------------------------------------------------------------
__global__ void repack_w(const float* __restrict__ w2, const float* __restrict__ w3,
                         __hip_bfloat16* __restrict__ ws)
{
    int tid = blockIdx.x * 256 + threadIdx.x;
    const int total2 = 9 * 4 * 8 * 64 * 8;   // 147456
    const int total3 = 9 * 4 * 4 * 64 * 8;   // 73728
    if (tid < total2) {
        int j = tid & 7;
        int l = (tid >> 3) & 63;
        int rest = tid >> 9;
        int n = rest & 7;
        int kidx = rest >> 3;        // tap*4+cs
        int cs = kidx & 3, tap = kidx >> 2;
        int ci = cs * 32 + ((l >> 4) << 3) + j;
        int co = (n << 4) + (l & 15);
        ws[tid] = __float2bfloat16(w2[(tap * 128 + ci) * 128 + co]);
    } else if (tid < total2 + total3) {
        int t3 = tid - total2;
        int j = t3 & 7;
        int l = (t3 >> 3) & 63;
        int rest = t3 >> 9;
        int n = rest & 3;
        int kidx = rest >> 2;
        int cs = kidx & 3, tap = kidx >> 2;
        int ci = cs * 32 + ((l >> 4) << 3) + j;
        int co = (n << 4) + (l & 15);
        ws[total2 + t3] = __float2bfloat16(w3[(tap * 128 + ci) * 64 + co]);
    }
}

// ---------------------------------------------------------------------------
// Fused network, one block per image.
// LDS union region s_u (25856 B):
//   phase A: act1 bf16 [101][128], XOR-swizzled, rows 0..99 + zero row 100
//   phase B: p2f f32 [26*128] at [0,13312)  (atomicMax pool staging)
//            p2b bf16 [26][128] swizzled at [13312,19968), zero row 25
// ---------------------------------------------------------------------------
__global__ __launch_bounds__(NT, 3)
void img2svg_fused(const float* __restrict__ data,
                   const float* __restrict__ w1, const float* __restrict__ b1,
                   const float* __restrict__ b2,
                   const float* __restrict__ b3,
                   const float* __restrict__ w4, const float* __restrict__ b4,
                   const float* __restrict__ wd1, const float* __restrict__ bd1,
                   const float* __restrict__ wd2, const float* __restrict__ bd2,
                   const __hip_bfloat16* __restrict__ wsb,
                   float* __restrict__ out)
{
    __shared__ __align__(16) unsigned char s_u[25856];
    __shared__ float s_act3[26 * 64];    // conv3 out f32 + zero row 25
    __shared__ float s_pool4[4 * 64];
    __shared__ float s_feat[64];
    __shared__ float s_h[32];

    const int t = threadIdx.x;
    const int img = blockIdx.x;
    const int w = t >> 6;
    const int lane = t & 63;
    const int kg = lane >> 4;
    const int l15 = lane & 15;

    // ---------------- P0: init ----------------
    if (t < 64) s_act3[1600 + t] = 0.f;
    s_pool4[t] = 0.f;
    // zero row 100 of act1b (swizzle is a within-row permutation; zeros anywhere)
    if (t < 128) *(unsigned short*)(s_u + (((25600 + 2 * t)) ^ 0x40)) = 0;

    // ---------------- P1: conv1 (1->128) -> act1 bf16 swizzled ----------------
    {
        const float* dimg = data + img * 100;
        for (int k = 0; k < 50; ++k) {
            int o = k * NT + t;
            int p = o >> 7, c = o & 127;
            int y = p / 10, x = p - 10 * y;     // p is wave-uniform
            float acc = b1[c];
#pragma unroll
            for (int tap = 0; tap < 9; ++tap) {
                int dy = tap / 3, dx = tap % 3;
                int ay = y + dy - 1, ax = x + dx - 1;
                float v = 0.f;
                if ((unsigned)ay < 10u && (unsigned)ax < 10u) v = dimg[ay * 10 + ax];
                acc = fmaf(v, w1[tap * 128 + c], acc);
            }
            float r = fmaxf(acc, 0.f);
            unsigned off = (unsigned)((p << 8) + 2 * c) ^ (unsigned)((p & 7) << 4);
            *(__hip_bfloat16*)(s_u + off) = __float2bfloat16(r);
        }
    }
    __syncthreads();

    // ---------------- P2: conv2 (128->128) implicit-GEMM MFMA ----------------
    // M = 112 (7 tiles, tile 7 junk for wm=1), N = 128 (8 tiles), K = 1152
    // wave (wm = w>>1, wn = w&1): M-tiles 4wm..4wm+3, N-tiles 4wn..4wn+3
    {
        const int wm = w >> 1, wn = w & 1;
        const uint32x4* pk2v = (const uint32x4*)wsb;

        f32x4 acc[4][4];
#pragma unroll
        for (int j = 0; j < 4; ++j) {
            float bj = b2[wn * 64 + j * 16 + l15];
#pragma unroll
            for (int mi = 0; mi < 4; ++mi) acc[mi][j] = (f32x4){bj, bj, bj, bj};
        }

        int py[4], px[4];
#pragma unroll
        for (int mi = 0; mi < 4; ++mi) {
            int pos = (4 * wm + mi) * 16 + l15;
            py[mi] = pos / 10;
            px[mi] = pos - 10 * py[mi];
        }

        uint32x4 Bc[4], Bn[4];
#pragma unroll
        for (int j = 0; j < 4; ++j) Bc[j] = pk2v[((wn * 4 + j) << 6) + lane];

        for (int tap = 0; tap < 9; ++tap) {
            const int dy = tap / 3, dx = tap - 3 * (tap / 3);
            int abase[4];
#pragma unroll
            for (int mi = 0; mi < 4; ++mi) {
                int ay = py[mi] + dy - 1, ax = px[mi] + dx - 1;
                int r = ((unsigned)ay < 10u && (unsigned)ax < 10u) ? ay * 10 + ax : 100;
                int e = (r & 7) << 4;
                abase[mi] = (r << 8) + (e & 64) + (((kg << 4)) ^ (e & 48));
            }
#pragma unroll
            for (int cs = 0; cs < 4; ++cs) {
                // prefetch next k-step's B fragments
                int nk = tap * 4 + cs + 1;
                if (cs < 3 || tap < 8) {
#pragma unroll
                    for (int j = 0; j < 4; ++j)
                        Bn[j] = pk2v[(((nk << 3) + wn * 4 + j) << 6) + lane];
                }
                bf16x8 A[4];
#pragma unroll
                for (int mi = 0; mi < 4; ++mi)
                    A[mi] = *(const bf16x8*)(const void*)(s_u + (abase[mi] ^ (cs << 6)));
#pragma unroll
                for (int mi = 0; mi < 4; ++mi)
#pragma unroll
                    for (int j = 0; j < 4; ++j)
                        acc[mi][j] = __builtin_amdgcn_mfma_f32_16x16x32_bf16(
                            A[mi], __builtin_bit_cast(bf16x8, Bc[j]), acc[mi][j], 0, 0, 0);
#pragma unroll
                for (int j = 0; j < 4; ++j) Bc[j] = Bn[j];
            }
        }
        __syncthreads();   // all waves done reading act1b

        // zero pool staging p2f (aliases act1b region)
        float* p2f = (float*)s_u;
        for (int i = t; i < 3328; i += NT) p2f[i] = 0.f;
        __syncthreads();

        // relu + 2x2 maxpool via atomicMax
#pragma unroll
        for (int mi = 0; mi < 4; ++mi) {
            int posb = (4 * wm + mi) * 16 + kg * 4;
#pragma unroll
            for (int j = 0; j < 4; ++j) {
                int co = wn * 64 + j * 16 + l15;
                float v0 = fmaxf(acc[mi][j][0], 0.f);
                float v1 = fmaxf(acc[mi][j][1], 0.f);
                float v2 = fmaxf(acc[mi][j][2], 0.f);
                float v3 = fmaxf(acc[mi][j][3], 0.f);
                float m01 = fmaxf(v0, v1);
                float m23 = fmaxf(v2, v3);
                if (posb < 100) {
                    int y = posb / 10, x = posb - 10 * y;
                    atomicMax((int*)&p2f[(((y >> 1) * 5 + (x >> 1)) << 7) + co],
                              __float_as_int(m01));
                }
                int pos2 = posb + 2;
                if (pos2 < 100) {
                    int y = pos2 / 10, x = pos2 - 10 * y;
                    atomicMax((int*)&p2f[(((y >> 1) * 5 + (x >> 1)) << 7) + co],
                              __float_as_int(m23));
                }
            }
        }
    }
    __syncthreads();

    // ---------------- P2b: convert p2f -> p2b bf16 swizzled ----------------
    {
        const float* p2f = (const float*)s_u;
        for (int i = t; i < 3328; i += NT) {
            int r = i >> 7, c = i & 127;
            float v = p2f[i];                       // row 25 already zero
            unsigned off = (unsigned)((r << 8) + 2 * c) ^ (unsigned)((r & 7) << 4);
            *(__hip_bfloat16*)(s_u + 13312 + off) = __float2bfloat16(v);
        }
    }
    __syncthreads();

    // ---------------- P3: conv3 (128->64) MFMA ----------------
    // M = 32 (2 tiles), N = 64 (4 tiles), K = 1152
    // wave: mt = w&1, ntp = w>>1 (n-tiles 2*ntp, 2*ntp+1)
    {
        const int mt = w & 1, ntp = w >> 1;
        const uint32x4* pk3v = (const uint32x4*)(const void*)((const char*)wsb + 294912);

        f32x4 c3[2];
#pragma unroll
        for (int j = 0; j < 2; ++j) {
            float bj = b3[ntp * 32 + j * 16 + l15];
            c3[j] = (f32x4){bj, bj, bj, bj};
        }
        int pos = mt * 16 + l15;
        int p3y = pos / 5, p3x = pos - 5 * (pos / 5);

        uint32x4 Bc[2], Bn[2];
#pragma unroll
        for (int j = 0; j < 2; ++j) Bc[j] = pk3v[((ntp * 2 + j) << 6) + lane];

        for (int tap = 0; tap < 9; ++tap) {
            const int dy = tap / 3, dx = tap - 3 * (tap / 3);
            int ay = p3y + dy - 1, ax = p3x + dx - 1;
            int r = ((unsigned)ay < 5u && (unsigned)ax < 5u) ? ay * 5 + ax : 25;
            int e = (r & 7) << 4;
            int ab = 13312 + (r << 8) + (e & 64) + (((kg << 4)) ^ (e & 48));
#pragma unroll
            for (int cs = 0; cs < 4; ++cs) {
                int nk = tap * 4 + cs + 1;
                if (cs < 3 || tap < 8) {
#pragma unroll
                    for (int j = 0; j < 2; ++j)
                        Bn[j] = pk3v[(((nk << 2) + ntp * 2 + j) << 6) + lane];
                }
                bf16x8 A = *(const bf16x8*)(const void*)(s_u + (ab ^ (cs << 6)));
#pragma unroll
                for (int j = 0; j < 2; ++j)
                    c3[j] = __builtin_amdgcn_mfma_f32_16x16x32_bf16(
                        A, __builtin_bit_cast(bf16x8, Bc[j]), c3[j], 0, 0, 0);
#pragma unroll
                for (int j = 0; j < 2; ++j) Bc[j] = Bn[j];
            }
        }
        // epilogue: relu, store f32 act3
#pragma unroll
        for (int j = 0; j < 2; ++j) {
            int co = ntp * 32 + j * 16 + l15;
#pragma unroll
            for (int rr = 0; rr < 4; ++rr) {
                int p = mt * 16 + kg * 4 + rr;
                if (p < 25) s_act3[p * 64 + co] = fmaxf(c3[j][rr], 0.f);
            }
        }
    }
    __syncthreads();

    // ---------------- P4: conv4 (64->64) vector f32 + 2x2 maxpool ----------------
    {
        const int cog = t & 31;
        const int co2 = cog << 1;
        const int pg = t >> 5;
        const int pA = pg, pB = pg + 8;
        const int ry0 = pA >> 2, rx0 = pA & 3;
        const int ry1 = pB >> 2, rx1 = pB & 3;

        float acc[2][2];
#pragma unroll
        for (int i = 0; i < 2; ++i) { float bi = b4[co2 + i]; acc[0][i] = bi; acc[1][i] = bi; }

        typedef float f2 __attribute__((ext_vector_type(2)));
        const f2* w4v = (const f2*)w4;

        for (int tap = 0; tap < 9; ++tap) {
            int dy = tap / 3, dx = tap - 3 * (tap / 3);
            int ay0 = ry0 + dy - 1, ax0 = rx0 + dx - 1;
            int ay1 = ry1 + dy - 1, ax1 = rx1 + dx - 1;
            int q0 = ((unsigned)ay0 < 5u && (unsigned)ax0 < 5u) ? ((ay0 * 5 + ax0) << 6) : 1600;
            int q1 = ((unsigned)ay1 < 5u && (unsigned)ax1 < 5u) ? ((ay1 * 5 + ax1) << 6) : 1600;

            for (int ci = 0; ci < 64; ci += 4) {
                f4 a0 = *(const f4*)&s_act3[q0 + ci];
                f4 a1 = *(const f4*)&s_act3[q1 + ci];
#pragma unroll
                for (int u = 0; u < 4; ++u) {
                    f2 wv = w4v[((tap << 6) + ci + u) * 32 + cog];
#pragma unroll
                    for (int i = 0; i < 2; ++i) {
                        acc[0][i] = fmaf(a0[u], wv[i], acc[0][i]);
                        acc[1][i] = fmaf(a1[u], wv[i], acc[1][i]);
                    }
                }
            }
        }
        const int cell0 = (ry0 >> 1) * 2 + (rx0 >> 1);
        const int cell1 = (ry1 >> 1) * 2 + (rx1 >> 1);
#pragma unroll
        for (int i = 0; i < 2; ++i) {
            float r0 = fmaxf(acc[0][i], 0.f);
            float r1 = fmaxf(acc[1][i], 0.f);
            atomicMax((int*)&s_pool4[cell0 * 64 + co2 + i], __float_as_int(r0));
            atomicMax((int*)&s_pool4[cell1 * 64 + co2 + i], __float_as_int(r1));
        }
    }
    __syncthreads();

    // ---------------- P5: mean + dense1 ----------------
    if (t < 64) {
        float f = 0.25f * (s_pool4[t] + s_pool4[64 + t] + s_pool4[128 + t] + s_pool4[192 + t]);
        s_feat[t] = f;
    }
    __syncthreads();
    if (t < 32) {
        float h = bd1[t];
        for (int i = 0; i < 64; ++i) h = fmaf(s_feat[i], wd1[i * 32 + t], h);
        s_h[t] = fmaxf(h, 0.f);
    }
    __syncthreads();

    // ---------------- P6: dense2 + sigmoid + bezier + round + sort + dedup ----------------
    if (t == 0) {
        float v[4];
#pragma unroll
        for (int o = 0; o < 4; ++o) {
            float vv = bd2[o];
            for (int i = 0; i < 32; ++i) vv = fmaf(s_h[i], wd2[i * 4 + o], vv);
            v[o] = 1.f / (1.f + expf(-vv));
        }
        float px[5], py[5], pp[5];
#pragma unroll
        for (int k = 0; k < 5; ++k) {
            float tk = 0.25f * (float)k;
            float gx = ((1.f - tk) * v[0] + tk * v[2]) * 10.f;
            float gy = ((1.f - tk) * v[1] + tk * v[3]) * 10.f;
            px[k] = rintf(gx);
            py[k] = rintf(gy);
            pp[k] = px[k] * 10.f + py[k];
        }
#pragma unroll
        for (int pass = 0; pass < 4; ++pass)
#pragma unroll
            for (int i = 0; i < 4 - pass; ++i) {
                bool sw = pp[i] > pp[i + 1];
                float a, b;
                a = pp[i]; b = pp[i + 1]; pp[i] = sw ? b : a; pp[i + 1] = sw ? a : b;
                a = px[i]; b = px[i + 1]; px[i] = sw ? b : a; px[i + 1] = sw ? a : b;
                a = py[i]; b = py[i + 1]; py[i] = sw ? b : a; py[i + 1] = sw ? a : b;
            }
        float* op = out + img * 10;
#pragma unroll
        for (int i = 0; i < 5; ++i) { op[2 * i] = -1.f; op[2 * i + 1] = -1.f; }
        int k2 = 0;
#pragma unroll
        for (int i = 0; i < 5; ++i) {
            bool keep;
            if (i == 0) keep = true;
            else keep = (fabsf(px[i] - px[i - 1]) + fabsf(py[i] - py[i - 1])) != 0.f;
            if (keep) {
                op[2 * k2] = px[i];
                op[2 * k2 + 1] = py[i];
                ++k2;
            }
        }
    }
}

extern "C" void kernel_launch(void* const* d_in, const int* in_sizes, int n_in,
                              void* d_out, int out_size, void* d_ws, size_t ws_size,
                              hipStream_t stream) {
    const float* data = (const float*)d_in[0];
    const float* w1  = (const float*)d_in[1];
    const float* b1  = (const float*)d_in[2];
    const float* w2  = (const float*)d_in[3];
    const float* b2  = (const float*)d_in[4];
    const float* w3  = (const float*)d_in[5];
    const float* b3  = (const float*)d_in[6];
    const float* w4  = (const float*)d_in[7];
    const float* b4  = (const float*)d_in[8];
    const float* wd1 = (const float*)d_in[9];
    const float* bd1 = (const float*)d_in[10];
    const float* wd2 = (const float*)d_in[11];
    const float* bd2 = (const float*)d_in[12];
    float* out = (float*)d_out;
    __hip_bfloat16* wsb = (__hip_bfloat16*)d_ws;

    // repack w2/w3 into MFMA B-fragment order (bf16) in workspace
    repack_w<<<864, 256, 0, stream>>>(w2, w3, wsb);

    int nimg = in_sizes[0] / 100;
    img2svg_fused<<<nimg, NT, 0, stream>>>(data, w1, b1, b2, b3, w4, b4,
                                           wd1, bd1, wd2, bd2, wsb, out);
}

// Round 4
// 675.007 us; speedup vs baseline: 12.0738x; 2.7964x over previous
//
#include <hip/hip_runtime.h>
#include <hip/hip_bf16.h>
#include <math.h>

typedef float f4 __attribute__((ext_vector_type(4)));
typedef float f32x4 __attribute__((ext_vector_type(4)));
typedef __bf16 bf16x8 __attribute__((ext_vector_type(8)));
typedef unsigned int uint32x4 __attribute__((ext_vector_type(4)));

#define NT 256

// ---------------------------------------------------------------------------
// Weight repack into MFMA B-fragment order (16x16x32 bf16).
// B-frag: lane l holds B[k = (l>>4)*8 + j][co = l&15], j = 0..7 (16B/lane).
// Element index: ((kstep * NTILES + n) * 64 + l) * 8 + j
//   pk2: kstep=tap*4+cs (36), NTILES=8  -> elems [0, 147456)
//   pk3: kstep=tap*4+cs (36), NTILES=4  -> elems [147456, 221184)
//   pk4: kstep=tap*2+half (18), NTILES=4 -> elems [221184, 258048)
//   pk1: kstep=0 (1, K=32 zero-padded), NTILES=8 -> elems [258048, 262144)
// ---------------------------------------------------------------------------
__global__ void repack_w(const float* __restrict__ w1, const float* __restrict__ w2,
                         const float* __restrict__ w3, const float* __restrict__ w4,
                         __hip_bfloat16* __restrict__ ws)
{
    int tid = blockIdx.x * 256 + threadIdx.x;
    const int T2 = 147456, T3 = 73728, T4 = 36864, T1 = 4096;
    if (tid < T2) {
        int j = tid & 7, l = (tid >> 3) & 63, rest = tid >> 9;
        int n = rest & 7, kidx = rest >> 3;      // tap*4+cs
        int cs = kidx & 3, tap = kidx >> 2;
        int ci = cs * 32 + ((l >> 4) << 3) + j;
        int co = (n << 4) + (l & 15);
        ws[tid] = __float2bfloat16(w2[(tap * 128 + ci) * 128 + co]);
    } else if (tid < T2 + T3) {
        int t3 = tid - T2;
        int j = t3 & 7, l = (t3 >> 3) & 63, rest = t3 >> 9;
        int n = rest & 3, kidx = rest >> 2;
        int cs = kidx & 3, tap = kidx >> 2;
        int ci = cs * 32 + ((l >> 4) << 3) + j;
        int co = (n << 4) + (l & 15);
        ws[tid] = __float2bfloat16(w3[(tap * 128 + ci) * 64 + co]);
    } else if (tid < T2 + T3 + T4) {
        int t4 = tid - T2 - T3;
        int j = t4 & 7, l = (t4 >> 3) & 63, rest = t4 >> 9;
        int n = rest & 3, ks = rest >> 2;        // tap*2+half
        int half = ks & 1, tap = ks >> 1;
        int ci = half * 32 + ((l >> 4) << 3) + j;
        int co = (n << 4) + (l & 15);
        ws[tid] = __float2bfloat16(w4[(tap * 64 + ci) * 64 + co]);
    } else if (tid < T2 + T3 + T4 + T1) {
        int t1 = tid - T2 - T3 - T4;
        int j = t1 & 7, l = (t1 >> 3) & 63, n = (t1 >> 9) & 7;
        int k = ((l >> 4) << 3) + j;             // tap index, 0..31
        int co = (n << 4) + (l & 15);
        float v = (k < 9) ? w1[k * 128 + co] : 0.f;
        ws[tid] = __float2bfloat16(v);
    }
}

// ---------------------------------------------------------------------------
// Fused network, one block per image. All activations in k-major fragment
// layout: addr = base + (ci>>3)*KBSTRIDE + row*16 + (ci&7)*2  (bf16).
// Per-lane A reads are then contiguous 16B units -> conflict-free.
//   act1T: base 0,     16 kb, stride 1616 (101 rows; row 100 = zero)
//   p2f:   f32 staging [0, 12800) after conv2
//   p2bT:  base 13312, 16 kb, stride 416 (26 rows; row 25 = zero)
//   act3T: base 19968,  8 kb, stride 416 (26 rows; row 25 = zero)
// ---------------------------------------------------------------------------
__global__ __launch_bounds__(NT, 4)
void img2svg_fused(const float* __restrict__ data,
                   const float* __restrict__ b1, const float* __restrict__ b2,
                   const float* __restrict__ b3, const float* __restrict__ b4,
                   const float* __restrict__ wd1, const float* __restrict__ bd1,
                   const float* __restrict__ wd2, const float* __restrict__ bd2,
                   const __hip_bfloat16* __restrict__ wsb,
                   float* __restrict__ out)
{
    __shared__ __align__(16) unsigned char s_u[25856];
    __shared__ float s_in[144];
    __shared__ float s_pool4[4 * 64];
    __shared__ float s_feat[64];
    __shared__ float s_h[32];

    const int t = threadIdx.x;
    const int img = blockIdx.x;
    const int w = t >> 6;
    const int lane = t & 63;
    const int kg = lane >> 4;
    const int l15 = lane & 15;
    const int kgbase1 = kg * 1616;
    const int kgbase2 = kg * 416;

    // ---------------- P0: stage input, zero rows ----------------
    if (t < 144) {
        int r = t / 12, c = t % 12;
        float v = 0.f;
        if (r >= 1 && r <= 10 && c >= 1 && c <= 10)
            v = data[img * 100 + (r - 1) * 10 + (c - 1)];
        s_in[t] = v;
    }
    if (t < 128)   // zero row 100 of act1T in all 16 kb blocks
        *(__bf16*)(s_u + (t >> 3) * 1616 + 1600 + (t & 7) * 2) = (__bf16)0.f;
    s_pool4[t] = 0.f;
    __syncthreads();

    // ---------------- P1: conv1 (1->128) via MFMA, K=32 zero-padded ----------------
    {
        const uint32x4* pk1v = (const uint32x4*)((const __hip_bfloat16*)wsb + 258048);
        uint32x4 B0 = pk1v[((w * 2 + 0) << 6) + lane];
        uint32x4 B1 = pk1v[((w * 2 + 1) << 6) + lane];
        float bj0 = b1[(w * 2 + 0) * 16 + l15];
        float bj1 = b1[(w * 2 + 1) * 16 + l15];
        const int kb0 = (w * 2 + 0) * 2 + (l15 >> 3);
        const int kb1 = (w * 2 + 1) * 2 + (l15 >> 3);
        const int cb = (l15 & 7) * 2;

        for (int mi = 0; mi < 7; ++mi) {
            int p_raw = mi * 16 + l15;
            int p = p_raw < 100 ? p_raw : 99;
            int y = p / 10, x = p - 10 * (p / 10);
            bf16x8 A = __builtin_bit_cast(bf16x8, (uint32x4){0, 0, 0, 0});
            if (kg == 0) {
#pragma unroll
                for (int j = 0; j < 8; ++j)
                    A[j] = (__bf16)s_in[(y + j / 3) * 12 + x + j % 3];
            } else if (kg == 1) {
                A[0] = (__bf16)s_in[(y + 2) * 12 + x + 2];
            }
            f32x4 c0 = (f32x4){bj0, bj0, bj0, bj0};
            f32x4 c1 = (f32x4){bj1, bj1, bj1, bj1};
            c0 = __builtin_amdgcn_mfma_f32_16x16x32_bf16(
                A, __builtin_bit_cast(bf16x8, B0), c0, 0, 0, 0);
            c1 = __builtin_amdgcn_mfma_f32_16x16x32_bf16(
                A, __builtin_bit_cast(bf16x8, B1), c1, 0, 0, 0);
#pragma unroll
            for (int rr = 0; rr < 4; ++rr) {
                int p_out = mi * 16 + kg * 4 + rr;
                if (p_out < 100) {
                    *(__bf16*)(s_u + kb0 * 1616 + p_out * 16 + cb) =
                        (__bf16)fmaxf(c0[rr], 0.f);
                    *(__bf16*)(s_u + kb1 * 1616 + p_out * 16 + cb) =
                        (__bf16)fmaxf(c1[rr], 0.f);
                }
            }
        }
    }
    __syncthreads();

    // ---------------- P2: conv2 (128->128) MFMA, M=112, N=128, K=1152 ----------------
    {
        const int wm = w >> 1, wn = w & 1;
        const uint32x4* pk2v = (const uint32x4*)wsb;

        f32x4 acc[4][4];
#pragma unroll
        for (int j = 0; j < 4; ++j) {
            float bj = b2[wn * 64 + j * 16 + l15];
#pragma unroll
            for (int mi = 0; mi < 4; ++mi) acc[mi][j] = (f32x4){bj, bj, bj, bj};
        }

        int py[4], px[4];
#pragma unroll
        for (int mi = 0; mi < 4; ++mi) {
            int pos = (4 * wm + mi) * 16 + l15;
            py[mi] = pos / 10;
            px[mi] = pos - 10 * py[mi];
        }

        uint32x4 Bc[4], Bn[4];
#pragma unroll
        for (int j = 0; j < 4; ++j) Bc[j] = pk2v[((wn * 4 + j) << 6) + lane];

        for (int tap = 0; tap < 9; ++tap) {
            const int dy = tap / 3, dx = tap - 3 * (tap / 3);
            int ao[4];
#pragma unroll
            for (int mi = 0; mi < 4; ++mi) {
                int ay = py[mi] + dy - 1, ax = px[mi] + dx - 1;
                int r = ((unsigned)ay < 10u && (unsigned)ax < 10u) ? ay * 10 + ax : 100;
                ao[mi] = (r << 4) + kgbase1;
            }
#pragma unroll
            for (int cs = 0; cs < 4; ++cs) {
                int nk = tap * 4 + cs + 1;
                if (nk < 36) {
#pragma unroll
                    for (int j = 0; j < 4; ++j)
                        Bn[j] = pk2v[(((nk << 3) + wn * 4 + j) << 6) + lane];
                }
                bf16x8 A[4];
#pragma unroll
                for (int mi = 0; mi < 4; ++mi)
                    A[mi] = *(const bf16x8*)(const void*)(s_u + cs * 6464 + ao[mi]);
#pragma unroll
                for (int mi = 0; mi < 4; ++mi)
#pragma unroll
                    for (int j = 0; j < 4; ++j)
                        acc[mi][j] = __builtin_amdgcn_mfma_f32_16x16x32_bf16(
                            A[mi], __builtin_bit_cast(bf16x8, Bc[j]), acc[mi][j], 0, 0, 0);
#pragma unroll
                for (int j = 0; j < 4; ++j) Bc[j] = Bn[j];
            }
        }
        __syncthreads();   // all waves done reading act1T

        // zero p2f staging + zero rows of p2bT / act3T
        float* p2f = (float*)s_u;
        for (int i = t; i < 3200; i += NT) p2f[i] = 0.f;
        if (t < 128)
            *(__bf16*)(s_u + 13312 + (t >> 3) * 416 + 400 + (t & 7) * 2) = (__bf16)0.f;
        if (t < 64)
            *(__bf16*)(s_u + 19968 + (t >> 3) * 416 + 400 + (t & 7) * 2) = (__bf16)0.f;
        __syncthreads();

        // relu + 2x2 maxpool via atomicMax into p2f
#pragma unroll
        for (int mi = 0; mi < 4; ++mi) {
            int posb = (4 * wm + mi) * 16 + kg * 4;
#pragma unroll
            for (int j = 0; j < 4; ++j) {
                int co = wn * 64 + j * 16 + l15;
                float m01 = fmaxf(fmaxf(acc[mi][j][0], acc[mi][j][1]), 0.f);
                float m23 = fmaxf(fmaxf(acc[mi][j][2], acc[mi][j][3]), 0.f);
                if (posb < 100) {
                    int y = posb / 10, x = posb - 10 * (posb / 10);
                    atomicMax((int*)&p2f[(((y >> 1) * 5 + (x >> 1)) << 7) + co],
                              __float_as_int(m01));
                }
                int pos2 = posb + 2;
                if (pos2 < 100) {
                    int y = pos2 / 10, x = pos2 - 10 * (pos2 / 10);
                    atomicMax((int*)&p2f[(((y >> 1) * 5 + (x >> 1)) << 7) + co],
                              __float_as_int(m23));
                }
            }
        }
    }
    __syncthreads();

    // ---------------- P2b: p2f f32 -> p2bT bf16 (k-major) ----------------
    {
        const float* p2f = (const float*)s_u;
        for (int i = t; i < 3200; i += NT) {
            int r = i >> 7, c = i & 127;
            float v = p2f[i];
            *(__bf16*)(s_u + 13312 + (c >> 3) * 416 + (r << 4) + (c & 7) * 2) = (__bf16)v;
        }
    }
    __syncthreads();

    // ---------------- P3: conv3 (128->64) MFMA, M=32, N=64, K=1152 ----------------
    {
        const int mt = w & 1, ntp = w >> 1;
        const uint32x4* pk3v = (const uint32x4*)((const __hip_bfloat16*)wsb + 147456);

        f32x4 c3[2];
#pragma unroll
        for (int j = 0; j < 2; ++j) {
            float bj = b3[ntp * 32 + j * 16 + l15];
            c3[j] = (f32x4){bj, bj, bj, bj};
        }
        int pos = mt * 16 + l15;
        int p3y = pos / 5, p3x = pos - 5 * (pos / 5);

        uint32x4 Bc[2], Bn[2];
#pragma unroll
        for (int j = 0; j < 2; ++j) Bc[j] = pk3v[((ntp * 2 + j) << 6) + lane];

        for (int tap = 0; tap < 9; ++tap) {
            const int dy = tap / 3, dx = tap - 3 * (tap / 3);
            int ay = p3y + dy - 1, ax = p3x + dx - 1;
            int r = ((unsigned)ay < 5u && (unsigned)ax < 5u) ? ay * 5 + ax : 25;
            int ao = 13312 + (r << 4) + kgbase2;
#pragma unroll
            for (int cs = 0; cs < 4; ++cs) {
                int nk = tap * 4 + cs + 1;
                if (nk < 36) {
#pragma unroll
                    for (int j = 0; j < 2; ++j)
                        Bn[j] = pk3v[(((nk << 2) + ntp * 2 + j) << 6) + lane];
                }
                bf16x8 A = *(const bf16x8*)(const void*)(s_u + cs * 1664 + ao);
#pragma unroll
                for (int j = 0; j < 2; ++j)
                    c3[j] = __builtin_amdgcn_mfma_f32_16x16x32_bf16(
                        A, __builtin_bit_cast(bf16x8, Bc[j]), c3[j], 0, 0, 0);
#pragma unroll
                for (int j = 0; j < 2; ++j) Bc[j] = Bn[j];
            }
        }
        // epilogue: relu, store bf16 act3T (k-major)
#pragma unroll
        for (int j = 0; j < 2; ++j) {
            int co = ntp * 32 + j * 16 + l15;
            int kb = co >> 3, cb = (co & 7) * 2;
#pragma unroll
            for (int rr = 0; rr < 4; ++rr) {
                int p = mt * 16 + kg * 4 + rr;
                if (p < 25)
                    *(__bf16*)(s_u + 19968 + kb * 416 + p * 16 + cb) =
                        (__bf16)fmaxf(c3[j][rr], 0.f);
            }
        }
    }
    __syncthreads();

    // ---------------- P4: conv4 (64->64) MFMA, M=16, N=64, K=576 + pool ----------------
    {
        const int nt = w;
        const uint32x4* pk4v = (const uint32x4*)((const __hip_bfloat16*)wsb + 221184);
        float bj = b4[nt * 16 + l15];
        f32x4 c4 = (f32x4){bj, bj, bj, bj};
        int py = l15 >> 2, px = l15 & 3;

        uint32x4 Bc = pk4v[(nt << 6) + lane], Bn;
        for (int ks = 0; ks < 18; ++ks) {
            if (ks < 17) Bn = pk4v[((((ks + 1) << 2) + nt) << 6) + lane];
            int half = ks & 1, tap = ks >> 1;
            int dy = tap / 3, dx = tap - 3 * (tap / 3);
            int ay = py + dy - 1, ax = px + dx - 1;
            int r = ((unsigned)ay < 5u && (unsigned)ax < 5u) ? ay * 5 + ax : 25;
            bf16x8 A = *(const bf16x8*)(const void*)(
                s_u + 19968 + (half * 4 + kg) * 416 + (r << 4));
            c4 = __builtin_amdgcn_mfma_f32_16x16x32_bf16(
                A, __builtin_bit_cast(bf16x8, Bc), c4, 0, 0, 0);
            Bc = Bn;
        }
#pragma unroll
        for (int rr = 0; rr < 4; ++rr) {
            int p = kg * 4 + rr;
            int cell = ((p >> 2) >> 1) * 2 + ((p & 3) >> 1);
            float rv = fmaxf(c4[rr], 0.f);
            atomicMax((int*)&s_pool4[cell * 64 + nt * 16 + l15], __float_as_int(rv));
        }
    }
    __syncthreads();

    // ---------------- P5: mean + dense1 ----------------
    if (t < 64) {
        float f = 0.25f * (s_pool4[t] + s_pool4[64 + t] + s_pool4[128 + t] + s_pool4[192 + t]);
        s_feat[t] = f;
    }
    __syncthreads();
    if (t < 32) {
        float h = bd1[t];
        for (int i = 0; i < 64; ++i) h = fmaf(s_feat[i], wd1[i * 32 + t], h);
        s_h[t] = fmaxf(h, 0.f);
    }
    __syncthreads();

    // ---------------- P6: dense2 + sigmoid + bezier + round + sort + dedup ----------------
    if (t == 0) {
        float v[4];
#pragma unroll
        for (int o = 0; o < 4; ++o) {
            float vv = bd2[o];
            for (int i = 0; i < 32; ++i) vv = fmaf(s_h[i], wd2[i * 4 + o], vv);
            v[o] = 1.f / (1.f + expf(-vv));
        }
        float px[5], py[5], pp[5];
#pragma unroll
        for (int k = 0; k < 5; ++k) {
            float tk = 0.25f * (float)k;
            float gx = ((1.f - tk) * v[0] + tk * v[2]) * 10.f;
            float gy = ((1.f - tk) * v[1] + tk * v[3]) * 10.f;
            px[k] = rintf(gx);
            py[k] = rintf(gy);
            pp[k] = px[k] * 10.f + py[k];
        }
#pragma unroll
        for (int pass = 0; pass < 4; ++pass)
#pragma unroll
            for (int i = 0; i < 4 - pass; ++i) {
                bool sw = pp[i] > pp[i + 1];
                float a, b;
                a = pp[i]; b = pp[i + 1]; pp[i] = sw ? b : a; pp[i + 1] = sw ? a : b;
                a = px[i]; b = px[i + 1]; px[i] = sw ? b : a; px[i + 1] = sw ? a : b;
                a = py[i]; b = py[i + 1]; py[i] = sw ? b : a; py[i + 1] = sw ? a : b;
            }
        float* op = out + img * 10;
#pragma unroll
        for (int i = 0; i < 5; ++i) { op[2 * i] = -1.f; op[2 * i + 1] = -1.f; }
        int k2 = 0;
#pragma unroll
        for (int i = 0; i < 5; ++i) {
            bool keep;
            if (i == 0) keep = true;
            else keep = (fabsf(px[i] - px[i - 1]) + fabsf(py[i] - py[i - 1])) != 0.f;
            if (keep) {
                op[2 * k2] = px[i];
                op[2 * k2 + 1] = py[i];
                ++k2;
            }
        }
    }
}

extern "C" void kernel_launch(void* const* d_in, const int* in_sizes, int n_in,
                              void* d_out, int out_size, void* d_ws, size_t ws_size,
                              hipStream_t stream) {
    const float* data = (const float*)d_in[0];
    const float* w1  = (const float*)d_in[1];
    const float* b1  = (const float*)d_in[2];
    const float* w2  = (const float*)d_in[3];
    const float* b2  = (const float*)d_in[4];
    const float* w3  = (const float*)d_in[5];
    const float* b3  = (const float*)d_in[6];
    const float* w4  = (const float*)d_in[7];
    const float* b4  = (const float*)d_in[8];
    const float* wd1 = (const float*)d_in[9];
    const float* bd1 = (const float*)d_in[10];
    const float* wd2 = (const float*)d_in[11];
    const float* bd2 = (const float*)d_in[12];
    float* out = (float*)d_out;
    __hip_bfloat16* wsb = (__hip_bfloat16*)d_ws;

    repack_w<<<1024, 256, 0, stream>>>(w1, w2, w3, w4, wsb);

    int nimg = in_sizes[0] / 100;
    img2svg_fused<<<nimg, NT, 0, stream>>>(data, b1, b2, b3, b4,
                                           wd1, bd1, wd2, bd2, wsb, out);
}

// Round 5
// 647.738 us; speedup vs baseline: 12.5821x; 1.0421x over previous
//
#include <hip/hip_runtime.h>
#include <hip/hip_bf16.h>
#include <math.h>

typedef float f4 __attribute__((ext_vector_type(4)));
typedef float f32x4 __attribute__((ext_vector_type(4)));
typedef __bf16 bf16x8 __attribute__((ext_vector_type(8)));
typedef unsigned int uint32x4 __attribute__((ext_vector_type(4)));

#define NT 256

// ---------------------------------------------------------------------------
// Weight repack into MFMA B-fragment order (16x16x32 bf16).
// B-frag: lane l holds B[k = (l>>4)*8 + j][co = l&15], j = 0..7 (16B/lane).
// Element index: ((kstep * NTILES + n) * 64 + l) * 8 + j
//   pk2: kstep=tap*4+cs (36), NTILES=8  -> elems [0, 147456)
//   pk3: kstep=tap*4+cs (36), NTILES=4  -> elems [147456, 221184)
//   pk4: kstep=tap*2+half (18), NTILES=4 -> elems [221184, 258048)
//   pk1: kstep=0 (1, K=32 zero-padded), NTILES=8 -> elems [258048, 262144)
// ---------------------------------------------------------------------------
__global__ void repack_w(const float* __restrict__ w1, const float* __restrict__ w2,
                         const float* __restrict__ w3, const float* __restrict__ w4,
                         __hip_bfloat16* __restrict__ ws)
{
    int tid = blockIdx.x * 256 + threadIdx.x;
    const int T2 = 147456, T3 = 73728, T4 = 36864, T1 = 4096;
    if (tid < T2) {
        int j = tid & 7, l = (tid >> 3) & 63, rest = tid >> 9;
        int n = rest & 7, kidx = rest >> 3;      // tap*4+cs
        int cs = kidx & 3, tap = kidx >> 2;
        int ci = cs * 32 + ((l >> 4) << 3) + j;
        int co = (n << 4) + (l & 15);
        ws[tid] = __float2bfloat16(w2[(tap * 128 + ci) * 128 + co]);
    } else if (tid < T2 + T3) {
        int t3 = tid - T2;
        int j = t3 & 7, l = (t3 >> 3) & 63, rest = t3 >> 9;
        int n = rest & 3, kidx = rest >> 2;
        int cs = kidx & 3, tap = kidx >> 2;
        int ci = cs * 32 + ((l >> 4) << 3) + j;
        int co = (n << 4) + (l & 15);
        ws[tid] = __float2bfloat16(w3[(tap * 128 + ci) * 64 + co]);
    } else if (tid < T2 + T3 + T4) {
        int t4 = tid - T2 - T3;
        int j = t4 & 7, l = (t4 >> 3) & 63, rest = t4 >> 9;
        int n = rest & 3, ks = rest >> 2;        // tap*2+half
        int half = ks & 1, tap = ks >> 1;
        int ci = half * 32 + ((l >> 4) << 3) + j;
        int co = (n << 4) + (l & 15);
        ws[tid] = __float2bfloat16(w4[(tap * 64 + ci) * 64 + co]);
    } else if (tid < T2 + T3 + T4 + T1) {
        int t1 = tid - T2 - T3 - T4;
        int j = t1 & 7, l = (t1 >> 3) & 63, n = (t1 >> 9) & 7;
        int k = ((l >> 4) << 3) + j;             // tap index, 0..31
        int co = (n << 4) + (l & 15);
        float v = (k < 9) ? w1[k * 128 + co] : 0.f;
        ws[tid] = __float2bfloat16(v);
    }
}

// ---------------------------------------------------------------------------
// Fused network, one block per image. All activations in k-major fragment
// layout: addr = base + (ci>>3)*KBSTRIDE + row*16 + (ci&7)*2  (bf16).
// Per-lane A reads are then contiguous 16B units -> conflict-free.
//   act1T: base 0,     16 kb, stride 1616 (101 rows; row 100 = zero)
//   p2f:   f32 staging [0, 12800) after conv2
//   p2bT:  base 13312, 16 kb, stride 416 (26 rows; row 25 = zero)
//   act3T: base 19968,  8 kb, stride 416 (26 rows; row 25 = zero)
// NOTE: min-waves/EU = 3 (NOT 4): at 4 the unified VGPR+AGPR budget is 128
// and conv2 (~130 live regs) spills -> 229 MB/dispatch scratch writes (r4).
// ---------------------------------------------------------------------------
__global__ __launch_bounds__(NT, 3)
void img2svg_fused(const float* __restrict__ data,
                   const float* __restrict__ b1, const float* __restrict__ b2,
                   const float* __restrict__ b3, const float* __restrict__ b4,
                   const float* __restrict__ wd1, const float* __restrict__ bd1,
                   const float* __restrict__ wd2, const float* __restrict__ bd2,
                   const __hip_bfloat16* __restrict__ wsb,
                   float* __restrict__ out)
{
    __shared__ __align__(16) unsigned char s_u[25856];
    __shared__ float s_in[144];
    __shared__ float s_pool4[4 * 64];
    __shared__ float s_feat[64];
    __shared__ float s_h[32];

    const int t = threadIdx.x;
    const int img = blockIdx.x;
    const int w = t >> 6;
    const int lane = t & 63;
    const int kg = lane >> 4;
    const int l15 = lane & 15;
    const int kgbase1 = kg * 1616;
    const int kgbase2 = kg * 416;

    // ---------------- P0: stage input, zero rows ----------------
    if (t < 144) {
        int r = t / 12, c = t % 12;
        float v = 0.f;
        if (r >= 1 && r <= 10 && c >= 1 && c <= 10)
            v = data[img * 100 + (r - 1) * 10 + (c - 1)];
        s_in[t] = v;
    }
    if (t < 128)   // zero row 100 of act1T in all 16 kb blocks
        *(__bf16*)(s_u + (t >> 3) * 1616 + 1600 + (t & 7) * 2) = (__bf16)0.f;
    s_pool4[t] = 0.f;
    __syncthreads();

    // ---------------- P1: conv1 (1->128) via MFMA, K=32 zero-padded ----------------
    {
        const uint32x4* pk1v = (const uint32x4*)((const __hip_bfloat16*)wsb + 258048);
        uint32x4 B0 = pk1v[((w * 2 + 0) << 6) + lane];
        uint32x4 B1 = pk1v[((w * 2 + 1) << 6) + lane];
        float bj0 = b1[(w * 2 + 0) * 16 + l15];
        float bj1 = b1[(w * 2 + 1) * 16 + l15];
        const int kb0 = (w * 2 + 0) * 2 + (l15 >> 3);
        const int kb1 = (w * 2 + 1) * 2 + (l15 >> 3);
        const int cb = (l15 & 7) * 2;

        for (int mi = 0; mi < 7; ++mi) {
            int p_raw = mi * 16 + l15;
            int p = p_raw < 100 ? p_raw : 99;
            int y = p / 10, x = p - 10 * (p / 10);
            bf16x8 A = __builtin_bit_cast(bf16x8, (uint32x4){0, 0, 0, 0});
            if (kg == 0) {
#pragma unroll
                for (int j = 0; j < 8; ++j)
                    A[j] = (__bf16)s_in[(y + j / 3) * 12 + x + j % 3];
            } else if (kg == 1) {
                A[0] = (__bf16)s_in[(y + 2) * 12 + x + 2];
            }
            f32x4 c0 = (f32x4){bj0, bj0, bj0, bj0};
            f32x4 c1 = (f32x4){bj1, bj1, bj1, bj1};
            c0 = __builtin_amdgcn_mfma_f32_16x16x32_bf16(
                A, __builtin_bit_cast(bf16x8, B0), c0, 0, 0, 0);
            c1 = __builtin_amdgcn_mfma_f32_16x16x32_bf16(
                A, __builtin_bit_cast(bf16x8, B1), c1, 0, 0, 0);
#pragma unroll
            for (int rr = 0; rr < 4; ++rr) {
                int p_out = mi * 16 + kg * 4 + rr;
                if (p_out < 100) {
                    *(__bf16*)(s_u + kb0 * 1616 + p_out * 16 + cb) =
                        (__bf16)fmaxf(c0[rr], 0.f);
                    *(__bf16*)(s_u + kb1 * 1616 + p_out * 16 + cb) =
                        (__bf16)fmaxf(c1[rr], 0.f);
                }
            }
        }
    }
    __syncthreads();

    // ---------------- P2: conv2 (128->128) MFMA, M=112, N=128, K=1152 ----------------
    {
        const int wm = w >> 1, wn = w & 1;
        const uint32x4* pk2v = (const uint32x4*)wsb;

        f32x4 acc[4][4];
#pragma unroll
        for (int j = 0; j < 4; ++j) {
            float bj = b2[wn * 64 + j * 16 + l15];
#pragma unroll
            for (int mi = 0; mi < 4; ++mi) acc[mi][j] = (f32x4){bj, bj, bj, bj};
        }

        int py[4], px[4];
#pragma unroll
        for (int mi = 0; mi < 4; ++mi) {
            int pos = (4 * wm + mi) * 16 + l15;
            py[mi] = pos / 10;
            px[mi] = pos - 10 * py[mi];
        }

        uint32x4 Bc[4], Bn[4];
#pragma unroll
        for (int j = 0; j < 4; ++j) Bc[j] = pk2v[((wn * 4 + j) << 6) + lane];

        for (int tap = 0; tap < 9; ++tap) {
            const int dy = tap / 3, dx = tap - 3 * (tap / 3);
            int ao[4];
#pragma unroll
            for (int mi = 0; mi < 4; ++mi) {
                int ay = py[mi] + dy - 1, ax = px[mi] + dx - 1;
                int r = ((unsigned)ay < 10u && (unsigned)ax < 10u) ? ay * 10 + ax : 100;
                ao[mi] = (r << 4) + kgbase1;
            }
#pragma unroll
            for (int cs = 0; cs < 4; ++cs) {
                int nk = tap * 4 + cs + 1;
                if (nk < 36) {
#pragma unroll
                    for (int j = 0; j < 4; ++j)
                        Bn[j] = pk2v[(((nk << 3) + wn * 4 + j) << 6) + lane];
                }
                bf16x8 A[4];
#pragma unroll
                for (int mi = 0; mi < 4; ++mi)
                    A[mi] = *(const bf16x8*)(const void*)(s_u + cs * 6464 + ao[mi]);
#pragma unroll
                for (int mi = 0; mi < 4; ++mi)
#pragma unroll
                    for (int j = 0; j < 4; ++j)
                        acc[mi][j] = __builtin_amdgcn_mfma_f32_16x16x32_bf16(
                            A[mi], __builtin_bit_cast(bf16x8, Bc[j]), acc[mi][j], 0, 0, 0);
#pragma unroll
                for (int j = 0; j < 4; ++j) Bc[j] = Bn[j];
            }
        }
        __syncthreads();   // all waves done reading act1T

        // zero p2f staging + zero rows of p2bT / act3T
        float* p2f = (float*)s_u;
        for (int i = t; i < 3200; i += NT) p2f[i] = 0.f;
        if (t < 128)
            *(__bf16*)(s_u + 13312 + (t >> 3) * 416 + 400 + (t & 7) * 2) = (__bf16)0.f;
        if (t < 64)
            *(__bf16*)(s_u + 19968 + (t >> 3) * 416 + 400 + (t & 7) * 2) = (__bf16)0.f;
        __syncthreads();

        // relu + 2x2 maxpool via atomicMax into p2f
#pragma unroll
        for (int mi = 0; mi < 4; ++mi) {
            int posb = (4 * wm + mi) * 16 + kg * 4;
#pragma unroll
            for (int j = 0; j < 4; ++j) {
                int co = wn * 64 + j * 16 + l15;
                float m01 = fmaxf(fmaxf(acc[mi][j][0], acc[mi][j][1]), 0.f);
                float m23 = fmaxf(fmaxf(acc[mi][j][2], acc[mi][j][3]), 0.f);
                if (posb < 100) {
                    int y = posb / 10, x = posb - 10 * (posb / 10);
                    atomicMax((int*)&p2f[(((y >> 1) * 5 + (x >> 1)) << 7) + co],
                              __float_as_int(m01));
                }
                int pos2 = posb + 2;
                if (pos2 < 100) {
                    int y = pos2 / 10, x = pos2 - 10 * (pos2 / 10);
                    atomicMax((int*)&p2f[(((y >> 1) * 5 + (x >> 1)) << 7) + co],
                              __float_as_int(m23));
                }
            }
        }
    }
    __syncthreads();

    // ---------------- P2b: p2f f32 -> p2bT bf16 (k-major) ----------------
    {
        const float* p2f = (const float*)s_u;
        for (int i = t; i < 3200; i += NT) {
            int r = i >> 7, c = i & 127;
            float v = p2f[i];
            *(__bf16*)(s_u + 13312 + (c >> 3) * 416 + (r << 4) + (c & 7) * 2) = (__bf16)v;
        }
    }
    __syncthreads();

    // ---------------- P3: conv3 (128->64) MFMA, M=32, N=64, K=1152 ----------------
    {
        const int mt = w & 1, ntp = w >> 1;
        const uint32x4* pk3v = (const uint32x4*)((const __hip_bfloat16*)wsb + 147456);

        f32x4 c3[2];
#pragma unroll
        for (int j = 0; j < 2; ++j) {
            float bj = b3[ntp * 32 + j * 16 + l15];
            c3[j] = (f32x4){bj, bj, bj, bj};
        }
        int pos = mt * 16 + l15;
        int p3y = pos / 5, p3x = pos - 5 * (pos / 5);

        uint32x4 Bc[2], Bn[2];
#pragma unroll
        for (int j = 0; j < 2; ++j) Bc[j] = pk3v[((ntp * 2 + j) << 6) + lane];

        for (int tap = 0; tap < 9; ++tap) {
            const int dy = tap / 3, dx = tap - 3 * (tap / 3);
            int ay = p3y + dy - 1, ax = p3x + dx - 1;
            int r = ((unsigned)ay < 5u && (unsigned)ax < 5u) ? ay * 5 + ax : 25;
            int ao = 13312 + (r << 4) + kgbase2;
#pragma unroll
            for (int cs = 0; cs < 4; ++cs) {
                int nk = tap * 4 + cs + 1;
                if (nk < 36) {
#pragma unroll
                    for (int j = 0; j < 2; ++j)
                        Bn[j] = pk3v[(((nk << 2) + ntp * 2 + j) << 6) + lane];
                }
                bf16x8 A = *(const bf16x8*)(const void*)(s_u + cs * 1664 + ao);
#pragma unroll
                for (int j = 0; j < 2; ++j)
                    c3[j] = __builtin_amdgcn_mfma_f32_16x16x32_bf16(
                        A, __builtin_bit_cast(bf16x8, Bc[j]), c3[j], 0, 0, 0);
#pragma unroll
                for (int j = 0; j < 2; ++j) Bc[j] = Bn[j];
            }
        }
        // epilogue: relu, store bf16 act3T (k-major)
#pragma unroll
        for (int j = 0; j < 2; ++j) {
            int co = ntp * 32 + j * 16 + l15;
            int kb = co >> 3, cb = (co & 7) * 2;
#pragma unroll
            for (int rr = 0; rr < 4; ++rr) {
                int p = mt * 16 + kg * 4 + rr;
                if (p < 25)
                    *(__bf16*)(s_u + 19968 + kb * 416 + p * 16 + cb) =
                        (__bf16)fmaxf(c3[j][rr], 0.f);
            }
        }
    }
    __syncthreads();

    // ---------------- P4: conv4 (64->64) MFMA, M=16, N=64, K=576 + pool ----------------
    {
        const int nt = w;
        const uint32x4* pk4v = (const uint32x4*)((const __hip_bfloat16*)wsb + 221184);
        float bj = b4[nt * 16 + l15];
        f32x4 c4 = (f32x4){bj, bj, bj, bj};
        int py = l15 >> 2, px = l15 & 3;

        uint32x4 Bc = pk4v[(nt << 6) + lane], Bn;
        for (int ks = 0; ks < 18; ++ks) {
            if (ks < 17) Bn = pk4v[((((ks + 1) << 2) + nt) << 6) + lane];
            int half = ks & 1, tap = ks >> 1;
            int dy = tap / 3, dx = tap - 3 * (tap / 3);
            int ay = py + dy - 1, ax = px + dx - 1;
            int r = ((unsigned)ay < 5u && (unsigned)ax < 5u) ? ay * 5 + ax : 25;
            bf16x8 A = *(const bf16x8*)(const void*)(
                s_u + 19968 + (half * 4 + kg) * 416 + (r << 4));
            c4 = __builtin_amdgcn_mfma_f32_16x16x32_bf16(
                A, __builtin_bit_cast(bf16x8, Bc), c4, 0, 0, 0);
            Bc = Bn;
        }
#pragma unroll
        for (int rr = 0; rr < 4; ++rr) {
            int p = kg * 4 + rr;
            int cell = ((p >> 2) >> 1) * 2 + ((p & 3) >> 1);
            float rv = fmaxf(c4[rr], 0.f);
            atomicMax((int*)&s_pool4[cell * 64 + nt * 16 + l15], __float_as_int(rv));
        }
    }
    __syncthreads();

    // ---------------- P5: mean + dense1 ----------------
    if (t < 64) {
        float f = 0.25f * (s_pool4[t] + s_pool4[64 + t] + s_pool4[128 + t] + s_pool4[192 + t]);
        s_feat[t] = f;
    }
    __syncthreads();
    if (t < 32) {
        float h = bd1[t];
        for (int i = 0; i < 64; ++i) h = fmaf(s_feat[i], wd1[i * 32 + t], h);
        s_h[t] = fmaxf(h, 0.f);
    }
    __syncthreads();

    // ---------------- P6: dense2 + sigmoid + bezier + round + sort + dedup ----------------
    if (t == 0) {
        float v[4];
#pragma unroll
        for (int o = 0; o < 4; ++o) {
            float vv = bd2[o];
            for (int i = 0; i < 32; ++i) vv = fmaf(s_h[i], wd2[i * 4 + o], vv);
            v[o] = 1.f / (1.f + expf(-vv));
        }
        float px[5], py[5], pp[5];
#pragma unroll
        for (int k = 0; k < 5; ++k) {
            float tk = 0.25f * (float)k;
            float gx = ((1.f - tk) * v[0] + tk * v[2]) * 10.f;
            float gy = ((1.f - tk) * v[1] + tk * v[3]) * 10.f;
            px[k] = rintf(gx);
            py[k] = rintf(gy);
            pp[k] = px[k] * 10.f + py[k];
        }
#pragma unroll
        for (int pass = 0; pass < 4; ++pass)
#pragma unroll
            for (int i = 0; i < 4 - pass; ++i) {
                bool sw = pp[i] > pp[i + 1];
                float a, b;
                a = pp[i]; b = pp[i + 1]; pp[i] = sw ? b : a; pp[i + 1] = sw ? a : b;
                a = px[i]; b = px[i + 1]; px[i] = sw ? b : a; px[i + 1] = sw ? a : b;
                a = py[i]; b = py[i + 1]; py[i] = sw ? b : a; py[i + 1] = sw ? a : b;
            }
        float* op = out + img * 10;
#pragma unroll
        for (int i = 0; i < 5; ++i) { op[2 * i] = -1.f; op[2 * i + 1] = -1.f; }
        int k2 = 0;
#pragma unroll
        for (int i = 0; i < 5; ++i) {
            bool keep;
            if (i == 0) keep = true;
            else keep = (fabsf(px[i] - px[i - 1]) + fabsf(py[i] - py[i - 1])) != 0.f;
            if (keep) {
                op[2 * k2] = px[i];
                op[2 * k2 + 1] = py[i];
                ++k2;
            }
        }
    }
}

extern "C" void kernel_launch(void* const* d_in, const int* in_sizes, int n_in,
                              void* d_out, int out_size, void* d_ws, size_t ws_size,
                              hipStream_t stream) {
    const float* data = (const float*)d_in[0];
    const float* w1  = (const float*)d_in[1];
    const float* b1  = (const float*)d_in[2];
    const float* w2  = (const float*)d_in[3];
    const float* b2  = (const float*)d_in[4];
    const float* w3  = (const float*)d_in[5];
    const float* b3  = (const float*)d_in[6];
    const float* w4  = (const float*)d_in[7];
    const float* b4  = (const float*)d_in[8];
    const float* wd1 = (const float*)d_in[9];
    const float* bd1 = (const float*)d_in[10];
    const float* wd2 = (const float*)d_in[11];
    const float* bd2 = (const float*)d_in[12];
    float* out = (float*)d_out;
    __hip_bfloat16* wsb = (__hip_bfloat16*)d_ws;

    repack_w<<<1024, 256, 0, stream>>>(w1, w2, w3, w4, wsb);

    int nimg = in_sizes[0] / 100;
    img2svg_fused<<<nimg, NT, 0, stream>>>(data, b1, b2, b3, b4,
                                           wd1, bd1, wd2, bd2, wsb, out);
}

// Round 6
// 611.690 us; speedup vs baseline: 13.3236x; 1.0589x over previous
//
#include <hip/hip_runtime.h>
#include <hip/hip_bf16.h>
#include <math.h>

typedef float f4 __attribute__((ext_vector_type(4)));
typedef float f32x4 __attribute__((ext_vector_type(4)));
typedef __bf16 bf16x8 __attribute__((ext_vector_type(8)));
typedef unsigned int uint32x4 __attribute__((ext_vector_type(4)));

#define NT 256

// ---------------------------------------------------------------------------
// Weight repack into MFMA B-fragment order (16x16x32 bf16).
// B-frag: lane l holds B[k = (l>>4)*8 + j][co = l&15], j = 0..7 (16B/lane).
// Element index: ((kstep * NTILES + n) * 64 + l) * 8 + j
//   pk2: kstep=tap*4+cs (36), NTILES=8  -> elems [0, 147456)
//   pk3: kstep=tap*4+cs (36), NTILES=4  -> elems [147456, 221184)
//   pk4: kstep=tap*2+half (18), NTILES=4 -> elems [221184, 258048)
//   pk1: kstep=0 (1, K=32 zero-padded), NTILES=8 -> elems [258048, 262144)
// ---------------------------------------------------------------------------
__global__ void repack_w(const float* __restrict__ w1, const float* __restrict__ w2,
                         const float* __restrict__ w3, const float* __restrict__ w4,
                         __hip_bfloat16* __restrict__ ws)
{
    int tid = blockIdx.x * 256 + threadIdx.x;
    const int T2 = 147456, T3 = 73728, T4 = 36864, T1 = 4096;
    if (tid < T2) {
        int j = tid & 7, l = (tid >> 3) & 63, rest = tid >> 9;
        int n = rest & 7, kidx = rest >> 3;      // tap*4+cs
        int cs = kidx & 3, tap = kidx >> 2;
        int ci = cs * 32 + ((l >> 4) << 3) + j;
        int co = (n << 4) + (l & 15);
        ws[tid] = __float2bfloat16(w2[(tap * 128 + ci) * 128 + co]);
    } else if (tid < T2 + T3) {
        int t3 = tid - T2;
        int j = t3 & 7, l = (t3 >> 3) & 63, rest = t3 >> 9;
        int n = rest & 3, kidx = rest >> 2;
        int cs = kidx & 3, tap = kidx >> 2;
        int ci = cs * 32 + ((l >> 4) << 3) + j;
        int co = (n << 4) + (l & 15);
        ws[tid] = __float2bfloat16(w3[(tap * 128 + ci) * 64 + co]);
    } else if (tid < T2 + T3 + T4) {
        int t4 = tid - T2 - T3;
        int j = t4 & 7, l = (t4 >> 3) & 63, rest = t4 >> 9;
        int n = rest & 3, ks = rest >> 2;        // tap*2+half
        int half = ks & 1, tap = ks >> 1;
        int ci = half * 32 + ((l >> 4) << 3) + j;
        int co = (n << 4) + (l & 15);
        ws[tid] = __float2bfloat16(w4[(tap * 64 + ci) * 64 + co]);
    } else if (tid < T2 + T3 + T4 + T1) {
        int t1 = tid - T2 - T3 - T4;
        int j = t1 & 7, l = (t1 >> 3) & 63, n = (t1 >> 9) & 7;
        int k = ((l >> 4) << 3) + j;             // tap index, 0..31
        int co = (n << 4) + (l & 15);
        float v = (k < 9) ? w1[k * 128 + co] : 0.f;
        ws[tid] = __float2bfloat16(v);
    }
}

// ---------------------------------------------------------------------------
// Fused network, one block per image. Activation layouts (k-major fragment):
//   addr = base + (ci>>3)*KBSTRIDE + row*16 + (ci&7)*2  (bf16)
//   act1T: base 0,     16 kb, stride 1616 (rows 0..99 + zero row 100)
//   xp:    f32 [50][128] x-pooled conv2 staging at [0, 25600)   (after conv2)
//   p2bT:  base 25600, 16 kb, stride 416 (rows 0..24 + zero row 25)
//   act3T: base 0,      8 kb, stride 416 (rows 0..24 + zero row 25)
// conv2 wave-split: each wave = 7 M-tiles x 2 N-tiles (M=112 exact, no junk
// tiles). Regs ~105 -> fits the 128-reg budget of min-waves=4 (r4 lesson:
// 16-acc layout at ~130 regs spills catastrophically at this bound).
// Pooling: x-pairs are rr-pairs of the C-frag -> in-register max; y-pairs
// folded in the P2b pass. No LDS atomics, no zero-fill.
// ---------------------------------------------------------------------------
__global__ __launch_bounds__(NT, 4)
void img2svg_fused(const float* __restrict__ data,
                   const float* __restrict__ b1, const float* __restrict__ b2,
                   const float* __restrict__ b3, const float* __restrict__ b4,
                   const float* __restrict__ wd1, const float* __restrict__ bd1,
                   const float* __restrict__ wd2, const float* __restrict__ bd2,
                   const __hip_bfloat16* __restrict__ wsb,
                   float* __restrict__ out)
{
    __shared__ __align__(16) unsigned char s_u[32256];
    __shared__ float s_in[144];
    __shared__ float s_pool4[4 * 64];
    __shared__ float s_feat[64];
    __shared__ float s_h[32];

    const int t = threadIdx.x;
    const int img = blockIdx.x;
    const int w = t >> 6;
    const int lane = t & 63;
    const int kg = lane >> 4;
    const int l15 = lane & 15;
    const int kgbase1 = kg * 1616;
    const int kgbase2 = kg * 416;

    // ---------------- P0: stage input, zero act1T row 100 ----------------
    if (t < 144) {
        int r = t / 12, c = t % 12;
        float v = 0.f;
        if (r >= 1 && r <= 10 && c >= 1 && c <= 10)
            v = data[img * 100 + (r - 1) * 10 + (c - 1)];
        s_in[t] = v;
    }
    if (t < 128)
        *(__bf16*)(s_u + (t >> 3) * 1616 + 1600 + (t & 7) * 2) = (__bf16)0.f;
    s_pool4[t] = 0.f;
    __syncthreads();

    // ---------------- P1: conv1 (1->128) via MFMA, K=32 zero-padded ----------------
    {
        const uint32x4* pk1v = (const uint32x4*)((const __hip_bfloat16*)wsb + 258048);
        uint32x4 B0 = pk1v[((w * 2 + 0) << 6) + lane];
        uint32x4 B1 = pk1v[((w * 2 + 1) << 6) + lane];
        float bj0 = b1[(w * 2 + 0) * 16 + l15];
        float bj1 = b1[(w * 2 + 1) * 16 + l15];
        const int kb0 = (w * 2 + 0) * 2 + (l15 >> 3);
        const int kb1 = (w * 2 + 1) * 2 + (l15 >> 3);
        const int cb = (l15 & 7) * 2;

        for (int mi = 0; mi < 7; ++mi) {
            int p_raw = mi * 16 + l15;
            int p = p_raw < 100 ? p_raw : 99;
            int y = p / 10, x = p - 10 * (p / 10);
            bf16x8 A = __builtin_bit_cast(bf16x8, (uint32x4){0, 0, 0, 0});
            if (kg == 0) {
#pragma unroll
                for (int j = 0; j < 8; ++j)
                    A[j] = (__bf16)s_in[(y + j / 3) * 12 + x + j % 3];
            } else if (kg == 1) {
                A[0] = (__bf16)s_in[(y + 2) * 12 + x + 2];
            }
            f32x4 c0 = (f32x4){bj0, bj0, bj0, bj0};
            f32x4 c1 = (f32x4){bj1, bj1, bj1, bj1};
            c0 = __builtin_amdgcn_mfma_f32_16x16x32_bf16(
                A, __builtin_bit_cast(bf16x8, B0), c0, 0, 0, 0);
            c1 = __builtin_amdgcn_mfma_f32_16x16x32_bf16(
                A, __builtin_bit_cast(bf16x8, B1), c1, 0, 0, 0);
#pragma unroll
            for (int rr = 0; rr < 4; ++rr) {
                int p_out = mi * 16 + kg * 4 + rr;
                if (p_out < 100) {
                    *(__bf16*)(s_u + kb0 * 1616 + p_out * 16 + cb) =
                        (__bf16)fmaxf(c0[rr], 0.f);
                    *(__bf16*)(s_u + kb1 * 1616 + p_out * 16 + cb) =
                        (__bf16)fmaxf(c1[rr], 0.f);
                }
            }
        }
    }
    __syncthreads();

    // ---------------- P2: conv2 (128->128) MFMA, 7 M-tiles x 2 N-tiles/wave ----------------
    {
        const uint32x4* pk2v = (const uint32x4*)wsb;

        f32x4 acc[7][2];
#pragma unroll
        for (int j = 0; j < 2; ++j) {
            float bj = b2[(w * 2 + j) * 16 + l15];
#pragma unroll
            for (int mi = 0; mi < 7; ++mi) acc[mi][j] = (f32x4){bj, bj, bj, bj};
        }

        int py[7], px[7];
#pragma unroll
        for (int mi = 0; mi < 7; ++mi) {
            int pos = mi * 16 + l15;
            py[mi] = pos / 10;
            px[mi] = pos - 10 * py[mi];
        }

        for (int tap = 0; tap < 9; ++tap) {
            const int dy = tap / 3, dx = tap - 3 * (tap / 3);
            int ao[7];
#pragma unroll
            for (int mi = 0; mi < 7; ++mi) {
                int ay = py[mi] + dy - 1, ax = px[mi] + dx - 1;
                int r = ((unsigned)ay < 10u && (unsigned)ax < 10u) ? ay * 10 + ax : 100;
                ao[mi] = (r << 4) + kgbase1;
            }
#pragma unroll
            for (int cs = 0; cs < 4; ++cs) {
                int ks = tap * 4 + cs;
                uint32x4 Bc0 = pk2v[(((ks << 3) + w * 2 + 0) << 6) + lane];
                uint32x4 Bc1 = pk2v[(((ks << 3) + w * 2 + 1) << 6) + lane];
#pragma unroll
                for (int mi = 0; mi < 7; ++mi) {
                    bf16x8 A = *(const bf16x8*)(const void*)(s_u + cs * 6464 + ao[mi]);
                    acc[mi][0] = __builtin_amdgcn_mfma_f32_16x16x32_bf16(
                        A, __builtin_bit_cast(bf16x8, Bc0), acc[mi][0], 0, 0, 0);
                    acc[mi][1] = __builtin_amdgcn_mfma_f32_16x16x32_bf16(
                        A, __builtin_bit_cast(bf16x8, Bc1), acc[mi][1], 0, 0, 0);
                }
            }
        }
        __syncthreads();   // all waves done reading act1T

        // relu + x-pool in-register -> xp[50][128] f32 (no atomics, no zero-fill)
        float* xp = (float*)s_u;
#pragma unroll
        for (int mi = 0; mi < 7; ++mi) {
            int posb = mi * 16 + kg * 4;
            if (mi < 6 || kg == 0) {
                int s = posb >> 1;               // x-pooled slot
#pragma unroll
                for (int j = 0; j < 2; ++j) {
                    int co = (w * 2 + j) * 16 + l15;
                    float m01 = fmaxf(fmaxf(acc[mi][j][0], acc[mi][j][1]), 0.f);
                    float m23 = fmaxf(fmaxf(acc[mi][j][2], acc[mi][j][3]), 0.f);
                    xp[s * 128 + co] = m01;
                    xp[(s + 1) * 128 + co] = m23;
                }
            }
        }
    }
    __syncthreads();

    // ---------------- P2b: y-pool + cvt -> p2bT bf16 (k-major); zero row 25 ----------------
    {
        const float* xp = (const float*)s_u;
        for (int i = t; i < 3200; i += NT) {
            int r = i >> 7, c = i & 127;
            int y2 = r / 5, x2 = r - 5 * y2;
            int s = y2 * 10 + x2;
            float v = fmaxf(xp[s * 128 + c], xp[(s + 5) * 128 + c]);
            *(__bf16*)(s_u + 25600 + (c >> 3) * 416 + (r << 4) + (c & 7) * 2) = (__bf16)v;
        }
        if (t < 128)
            *(__bf16*)(s_u + 25600 + (t >> 3) * 416 + 400 + (t & 7) * 2) = (__bf16)0.f;
    }
    __syncthreads();

    // ---------------- P3: conv3 (128->64) MFMA, M=32, N=64, K=1152 ----------------
    {
        if (t < 64)   // zero act3T row 25 (xp is dead now; act3T base 0)
            *(__bf16*)(s_u + (t >> 3) * 416 + 400 + (t & 7) * 2) = (__bf16)0.f;

        const int mt = w & 1, ntp = w >> 1;
        const uint32x4* pk3v = (const uint32x4*)((const __hip_bfloat16*)wsb + 147456);

        f32x4 c3[2];
#pragma unroll
        for (int j = 0; j < 2; ++j) {
            float bj = b3[ntp * 32 + j * 16 + l15];
            c3[j] = (f32x4){bj, bj, bj, bj};
        }
        int pos = mt * 16 + l15;
        int p3y = pos / 5, p3x = pos - 5 * (pos / 5);

        uint32x4 Bc[2], Bn[2];
#pragma unroll
        for (int j = 0; j < 2; ++j) Bc[j] = pk3v[((ntp * 2 + j) << 6) + lane];

        for (int tap = 0; tap < 9; ++tap) {
            const int dy = tap / 3, dx = tap - 3 * (tap / 3);
            int ay = p3y + dy - 1, ax = p3x + dx - 1;
            int r = ((unsigned)ay < 5u && (unsigned)ax < 5u) ? ay * 5 + ax : 25;
            int ao = 25600 + (r << 4) + kgbase2;
#pragma unroll
            for (int cs = 0; cs < 4; ++cs) {
                int nk = tap * 4 + cs + 1;
                if (nk < 36) {
#pragma unroll
                    for (int j = 0; j < 2; ++j)
                        Bn[j] = pk3v[(((nk << 2) + ntp * 2 + j) << 6) + lane];
                }
                bf16x8 A = *(const bf16x8*)(const void*)(s_u + cs * 1664 + ao);
#pragma unroll
                for (int j = 0; j < 2; ++j)
                    c3[j] = __builtin_amdgcn_mfma_f32_16x16x32_bf16(
                        A, __builtin_bit_cast(bf16x8, Bc[j]), c3[j], 0, 0, 0);
#pragma unroll
                for (int j = 0; j < 2; ++j) Bc[j] = Bn[j];
            }
        }
        // epilogue: relu, store bf16 act3T (k-major, base 0)
#pragma unroll
        for (int j = 0; j < 2; ++j) {
            int co = ntp * 32 + j * 16 + l15;
            int kb = co >> 3, cb = (co & 7) * 2;
#pragma unroll
            for (int rr = 0; rr < 4; ++rr) {
                int p = mt * 16 + kg * 4 + rr;
                if (p < 25)
                    *(__bf16*)(s_u + kb * 416 + p * 16 + cb) =
                        (__bf16)fmaxf(c3[j][rr], 0.f);
            }
        }
    }
    __syncthreads();

    // ---------------- P4: conv4 (64->64) MFMA, M=16, N=64, K=576 + pool ----------------
    {
        const int nt = w;
        const uint32x4* pk4v = (const uint32x4*)((const __hip_bfloat16*)wsb + 221184);
        float bj = b4[nt * 16 + l15];
        f32x4 c4 = (f32x4){bj, bj, bj, bj};
        int py = l15 >> 2, px = l15 & 3;

        uint32x4 Bc = pk4v[(nt << 6) + lane], Bn;
        for (int ks = 0; ks < 18; ++ks) {
            if (ks < 17) Bn = pk4v[((((ks + 1) << 2) + nt) << 6) + lane];
            int half = ks & 1, tap = ks >> 1;
            int dy = tap / 3, dx = tap - 3 * (tap / 3);
            int ay = py + dy - 1, ax = px + dx - 1;
            int r = ((unsigned)ay < 5u && (unsigned)ax < 5u) ? ay * 5 + ax : 25;
            bf16x8 A = *(const bf16x8*)(const void*)(
                s_u + (half * 4 + kg) * 416 + (r << 4));
            c4 = __builtin_amdgcn_mfma_f32_16x16x32_bf16(
                A, __builtin_bit_cast(bf16x8, Bc), c4, 0, 0, 0);
            Bc = Bn;
        }
#pragma unroll
        for (int rr = 0; rr < 4; ++rr) {
            int p = kg * 4 + rr;
            int cell = ((p >> 2) >> 1) * 2 + ((p & 3) >> 1);
            float rv = fmaxf(c4[rr], 0.f);
            atomicMax((int*)&s_pool4[cell * 64 + nt * 16 + l15], __float_as_int(rv));
        }
    }
    __syncthreads();

    // ---------------- P5: mean + dense1 ----------------
    if (t < 64) {
        float f = 0.25f * (s_pool4[t] + s_pool4[64 + t] + s_pool4[128 + t] + s_pool4[192 + t]);
        s_feat[t] = f;
    }
    __syncthreads();
    if (t < 32) {
        float h = bd1[t];
        for (int i = 0; i < 64; ++i) h = fmaf(s_feat[i], wd1[i * 32 + t], h);
        s_h[t] = fmaxf(h, 0.f);
    }
    __syncthreads();

    // ---------------- P6: dense2 + sigmoid + bezier + round + sort + dedup ----------------
    if (t == 0) {
        float v[4];
#pragma unroll
        for (int o = 0; o < 4; ++o) {
            float vv = bd2[o];
            for (int i = 0; i < 32; ++i) vv = fmaf(s_h[i], wd2[i * 4 + o], vv);
            v[o] = 1.f / (1.f + expf(-vv));
        }
        float px[5], py[5], pp[5];
#pragma unroll
        for (int k = 0; k < 5; ++k) {
            float tk = 0.25f * (float)k;
            float gx = ((1.f - tk) * v[0] + tk * v[2]) * 10.f;
            float gy = ((1.f - tk) * v[1] + tk * v[3]) * 10.f;
            px[k] = rintf(gx);
            py[k] = rintf(gy);
            pp[k] = px[k] * 10.f + py[k];
        }
#pragma unroll
        for (int pass = 0; pass < 4; ++pass)
#pragma unroll
            for (int i = 0; i < 4 - pass; ++i) {
                bool sw = pp[i] > pp[i + 1];
                float a, b;
                a = pp[i]; b = pp[i + 1]; pp[i] = sw ? b : a; pp[i + 1] = sw ? a : b;
                a = px[i]; b = px[i + 1]; px[i] = sw ? b : a; px[i + 1] = sw ? a : b;
                a = py[i]; b = py[i + 1]; py[i] = sw ? b : a; py[i + 1] = sw ? a : b;
            }
        float* op = out + img * 10;
#pragma unroll
        for (int i = 0; i < 5; ++i) { op[2 * i] = -1.f; op[2 * i + 1] = -1.f; }
        int k2 = 0;
#pragma unroll
        for (int i = 0; i < 5; ++i) {
            bool keep;
            if (i == 0) keep = true;
            else keep = (fabsf(px[i] - px[i - 1]) + fabsf(py[i] - py[i - 1])) != 0.f;
            if (keep) {
                op[2 * k2] = px[i];
                op[2 * k2 + 1] = py[i];
                ++k2;
            }
        }
    }
}

extern "C" void kernel_launch(void* const* d_in, const int* in_sizes, int n_in,
                              void* d_out, int out_size, void* d_ws, size_t ws_size,
                              hipStream_t stream) {
    const float* data = (const float*)d_in[0];
    const float* w1  = (const float*)d_in[1];
    const float* b1  = (const float*)d_in[2];
    const float* w2  = (const float*)d_in[3];
    const float* b2  = (const float*)d_in[4];
    const float* w3  = (const float*)d_in[5];
    const float* b3  = (const float*)d_in[6];
    const float* w4  = (const float*)d_in[7];
    const float* b4  = (const float*)d_in[8];
    const float* wd1 = (const float*)d_in[9];
    const float* bd1 = (const float*)d_in[10];
    const float* wd2 = (const float*)d_in[11];
    const float* bd2 = (const float*)d_in[12];
    float* out = (float*)d_out;
    __hip_bfloat16* wsb = (__hip_bfloat16*)d_ws;

    repack_w<<<1024, 256, 0, stream>>>(w1, w2, w3, w4, wsb);

    int nimg = in_sizes[0] / 100;
    img2svg_fused<<<nimg, NT, 0, stream>>>(data, b1, b2, b3, b4,
                                           wd1, bd1, wd2, bd2, wsb, out);
}

// Round 7
// 605.919 us; speedup vs baseline: 13.4505x; 1.0095x over previous
//
#include <hip/hip_runtime.h>
#include <hip/hip_bf16.h>
#include <math.h>

typedef float f4 __attribute__((ext_vector_type(4)));
typedef float f32x4 __attribute__((ext_vector_type(4)));
typedef __bf16 bf16x8 __attribute__((ext_vector_type(8)));
typedef unsigned int uint32x4 __attribute__((ext_vector_type(4)));

#define NT 256

// ---------------------------------------------------------------------------
// Weight repack into MFMA B-fragment order (16x16x32 bf16).
// B-frag: lane l holds B[k = (l>>4)*8 + j][co = l&15], j = 0..7 (16B/lane).
// Element index: ((kstep * NTILES + n) * 64 + l) * 8 + j
//   pk2: kstep=tap*4+cs (36), NTILES=8  -> elems [0, 147456)
//   pk3: kstep=tap*4+cs (36), NTILES=4  -> elems [147456, 221184)
//   pk4: kstep=tap*2+half (18), NTILES=4 -> elems [221184, 258048)
//   pk1: kstep=0 (1, K=32 zero-padded), NTILES=8 -> elems [258048, 262144)
// ---------------------------------------------------------------------------
__global__ void repack_w(const float* __restrict__ w1, const float* __restrict__ w2,
                         const float* __restrict__ w3, const float* __restrict__ w4,
                         __hip_bfloat16* __restrict__ ws)
{
    int tid = blockIdx.x * 256 + threadIdx.x;
    const int T2 = 147456, T3 = 73728, T4 = 36864, T1 = 4096;
    if (tid < T2) {
        int j = tid & 7, l = (tid >> 3) & 63, rest = tid >> 9;
        int n = rest & 7, kidx = rest >> 3;      // tap*4+cs
        int cs = kidx & 3, tap = kidx >> 2;
        int ci = cs * 32 + ((l >> 4) << 3) + j;
        int co = (n << 4) + (l & 15);
        ws[tid] = __float2bfloat16(w2[(tap * 128 + ci) * 128 + co]);
    } else if (tid < T2 + T3) {
        int t3 = tid - T2;
        int j = t3 & 7, l = (t3 >> 3) & 63, rest = t3 >> 9;
        int n = rest & 3, kidx = rest >> 2;
        int cs = kidx & 3, tap = kidx >> 2;
        int ci = cs * 32 + ((l >> 4) << 3) + j;
        int co = (n << 4) + (l & 15);
        ws[tid] = __float2bfloat16(w3[(tap * 128 + ci) * 64 + co]);
    } else if (tid < T2 + T3 + T4) {
        int t4 = tid - T2 - T3;
        int j = t4 & 7, l = (t4 >> 3) & 63, rest = t4 >> 9;
        int n = rest & 3, ks = rest >> 2;        // tap*2+half
        int half = ks & 1, tap = ks >> 1;
        int ci = half * 32 + ((l >> 4) << 3) + j;
        int co = (n << 4) + (l & 15);
        ws[tid] = __float2bfloat16(w4[(tap * 64 + ci) * 64 + co]);
    } else if (tid < T2 + T3 + T4 + T1) {
        int t1 = tid - T2 - T3 - T4;
        int j = t1 & 7, l = (t1 >> 3) & 63, n = (t1 >> 9) & 7;
        int k = ((l >> 4) << 3) + j;             // tap index, 0..31
        int co = (n << 4) + (l & 15);
        float v = (k < 9) ? w1[k * 128 + co] : 0.f;
        ws[tid] = __float2bfloat16(v);
    }
}

// ---------------------------------------------------------------------------
// Fused network, one block per image. Activation layouts (k-major fragment):
//   addr = base + (ci>>3)*KBSTRIDE + row*16 + (ci&7)*2  (bf16)
//   act1T: base 0,     16 kb, stride 1616 (rows 0..99 + zero row 100)
//   xp:    f32 [50][128] x-pooled conv2 staging at [0, 25600)   (after conv2)
//   p2bT:  base 25600, 16 kb, stride 416 (rows 0..24 + zero row 25)
//   act3T: base 0,      8 kb, stride 416 (rows 0..24 + zero row 25)
// conv2: each wave = 7 M-tiles x 2 N-tiles (M=112 exact) WITH next-k-step
// B-fragment prefetch (Bn) -- L2 load latency hidden under the 14-MFMA burst.
// min-waves/EU = 3: the prefetch layout (~115 regs) fits the 170-reg budget;
// at 4 (128 regs) the compiler spills -> 132-229 MB/dispatch scratch (r4/r6).
// Pooling: x-pairs in-register (rr pairs of C-frag); y-pairs in P2b pass.
// ---------------------------------------------------------------------------
__global__ __launch_bounds__(NT, 3)
void img2svg_fused(const float* __restrict__ data,
                   const float* __restrict__ b1, const float* __restrict__ b2,
                   const float* __restrict__ b3, const float* __restrict__ b4,
                   const float* __restrict__ wd1, const float* __restrict__ bd1,
                   const float* __restrict__ wd2, const float* __restrict__ bd2,
                   const __hip_bfloat16* __restrict__ wsb,
                   float* __restrict__ out)
{
    __shared__ __align__(16) unsigned char s_u[32256];
    __shared__ float s_in[144];
    __shared__ float s_pool4[4 * 64];
    __shared__ float s_feat[64];
    __shared__ float s_h[32];

    const int t = threadIdx.x;
    const int img = blockIdx.x;
    const int w = t >> 6;
    const int lane = t & 63;
    const int kg = lane >> 4;
    const int l15 = lane & 15;
    const int kgbase1 = kg * 1616;
    const int kgbase2 = kg * 416;

    // ---------------- P0: stage input, zero act1T row 100 ----------------
    if (t < 144) {
        int r = t / 12, c = t % 12;
        float v = 0.f;
        if (r >= 1 && r <= 10 && c >= 1 && c <= 10)
            v = data[img * 100 + (r - 1) * 10 + (c - 1)];
        s_in[t] = v;
    }
    if (t < 128)
        *(__bf16*)(s_u + (t >> 3) * 1616 + 1600 + (t & 7) * 2) = (__bf16)0.f;
    s_pool4[t] = 0.f;
    __syncthreads();

    // ---------------- P1: conv1 (1->128) via MFMA, K=32 zero-padded ----------------
    {
        const uint32x4* pk1v = (const uint32x4*)((const __hip_bfloat16*)wsb + 258048);
        uint32x4 B0 = pk1v[((w * 2 + 0) << 6) + lane];
        uint32x4 B1 = pk1v[((w * 2 + 1) << 6) + lane];
        float bj0 = b1[(w * 2 + 0) * 16 + l15];
        float bj1 = b1[(w * 2 + 1) * 16 + l15];
        const int kb0 = (w * 2 + 0) * 2 + (l15 >> 3);
        const int kb1 = (w * 2 + 1) * 2 + (l15 >> 3);
        const int cb = (l15 & 7) * 2;

        for (int mi = 0; mi < 7; ++mi) {
            int p_raw = mi * 16 + l15;
            int p = p_raw < 100 ? p_raw : 99;
            int y = p / 10, x = p - 10 * (p / 10);
            bf16x8 A = __builtin_bit_cast(bf16x8, (uint32x4){0, 0, 0, 0});
            if (kg == 0) {
#pragma unroll
                for (int j = 0; j < 8; ++j)
                    A[j] = (__bf16)s_in[(y + j / 3) * 12 + x + j % 3];
            } else if (kg == 1) {
                A[0] = (__bf16)s_in[(y + 2) * 12 + x + 2];
            }
            f32x4 c0 = (f32x4){bj0, bj0, bj0, bj0};
            f32x4 c1 = (f32x4){bj1, bj1, bj1, bj1};
            c0 = __builtin_amdgcn_mfma_f32_16x16x32_bf16(
                A, __builtin_bit_cast(bf16x8, B0), c0, 0, 0, 0);
            c1 = __builtin_amdgcn_mfma_f32_16x16x32_bf16(
                A, __builtin_bit_cast(bf16x8, B1), c1, 0, 0, 0);
#pragma unroll
            for (int rr = 0; rr < 4; ++rr) {
                int p_out = mi * 16 + kg * 4 + rr;
                if (p_out < 100) {
                    *(__bf16*)(s_u + kb0 * 1616 + p_out * 16 + cb) =
                        (__bf16)fmaxf(c0[rr], 0.f);
                    *(__bf16*)(s_u + kb1 * 1616 + p_out * 16 + cb) =
                        (__bf16)fmaxf(c1[rr], 0.f);
                }
            }
        }
    }
    __syncthreads();

    // ---------------- P2: conv2 (128->128) MFMA, 7 M x 2 N per wave, B-prefetch ----------------
    {
        const uint32x4* pk2v = (const uint32x4*)wsb;

        f32x4 acc[7][2];
#pragma unroll
        for (int j = 0; j < 2; ++j) {
            float bj = b2[(w * 2 + j) * 16 + l15];
#pragma unroll
            for (int mi = 0; mi < 7; ++mi) acc[mi][j] = (f32x4){bj, bj, bj, bj};
        }

        int py[7], px[7];
#pragma unroll
        for (int mi = 0; mi < 7; ++mi) {
            int pos = mi * 16 + l15;
            py[mi] = pos / 10;
            px[mi] = pos - 10 * py[mi];
        }

        uint32x4 Bc0 = pk2v[((w * 2 + 0) << 6) + lane];
        uint32x4 Bc1 = pk2v[((w * 2 + 1) << 6) + lane];

        for (int tap = 0; tap < 9; ++tap) {
            const int dy = tap / 3, dx = tap - 3 * (tap / 3);
            int ao[7];
#pragma unroll
            for (int mi = 0; mi < 7; ++mi) {
                int ay = py[mi] + dy - 1, ax = px[mi] + dx - 1;
                int r = ((unsigned)ay < 10u && (unsigned)ax < 10u) ? ay * 10 + ax : 100;
                ao[mi] = (r << 4) + kgbase1;
            }
#pragma unroll
            for (int cs = 0; cs < 4; ++cs) {
                int nk = tap * 4 + cs + 1;
                uint32x4 Bn0, Bn1;
                if (nk < 36) {
                    Bn0 = pk2v[(((nk << 3) + w * 2 + 0) << 6) + lane];
                    Bn1 = pk2v[(((nk << 3) + w * 2 + 1) << 6) + lane];
                }
#pragma unroll
                for (int mi = 0; mi < 7; ++mi) {
                    bf16x8 A = *(const bf16x8*)(const void*)(s_u + cs * 6464 + ao[mi]);
                    acc[mi][0] = __builtin_amdgcn_mfma_f32_16x16x32_bf16(
                        A, __builtin_bit_cast(bf16x8, Bc0), acc[mi][0], 0, 0, 0);
                    acc[mi][1] = __builtin_amdgcn_mfma_f32_16x16x32_bf16(
                        A, __builtin_bit_cast(bf16x8, Bc1), acc[mi][1], 0, 0, 0);
                }
                Bc0 = Bn0;
                Bc1 = Bn1;
            }
        }
        __syncthreads();   // all waves done reading act1T

        // relu + x-pool in-register -> xp[50][128] f32 (no atomics, no zero-fill)
        float* xp = (float*)s_u;
#pragma unroll
        for (int mi = 0; mi < 7; ++mi) {
            int posb = mi * 16 + kg * 4;
            if (mi < 6 || kg == 0) {
                int s = posb >> 1;               // x-pooled slot
#pragma unroll
                for (int j = 0; j < 2; ++j) {
                    int co = (w * 2 + j) * 16 + l15;
                    float m01 = fmaxf(fmaxf(acc[mi][j][0], acc[mi][j][1]), 0.f);
                    float m23 = fmaxf(fmaxf(acc[mi][j][2], acc[mi][j][3]), 0.f);
                    xp[s * 128 + co] = m01;
                    xp[(s + 1) * 128 + co] = m23;
                }
            }
        }
    }
    __syncthreads();

    // ---------------- P2b: y-pool + cvt -> p2bT bf16 (k-major); zero row 25 ----------------
    {
        const float* xp = (const float*)s_u;
        for (int i = t; i < 3200; i += NT) {
            int r = i >> 7, c = i & 127;
            int y2 = r / 5, x2 = r - 5 * y2;
            int s = y2 * 10 + x2;
            float v = fmaxf(xp[s * 128 + c], xp[(s + 5) * 128 + c]);
            *(__bf16*)(s_u + 25600 + (c >> 3) * 416 + (r << 4) + (c & 7) * 2) = (__bf16)v;
        }
        if (t < 128)
            *(__bf16*)(s_u + 25600 + (t >> 3) * 416 + 400 + (t & 7) * 2) = (__bf16)0.f;
    }
    __syncthreads();

    // ---------------- P3: conv3 (128->64) MFMA, M=32, N=64, K=1152 ----------------
    {
        if (t < 64)   // zero act3T row 25 (xp is dead now; act3T base 0)
            *(__bf16*)(s_u + (t >> 3) * 416 + 400 + (t & 7) * 2) = (__bf16)0.f;

        const int mt = w & 1, ntp = w >> 1;
        const uint32x4* pk3v = (const uint32x4*)((const __hip_bfloat16*)wsb + 147456);

        f32x4 c3[2];
#pragma unroll
        for (int j = 0; j < 2; ++j) {
            float bj = b3[ntp * 32 + j * 16 + l15];
            c3[j] = (f32x4){bj, bj, bj, bj};
        }
        int pos = mt * 16 + l15;
        int p3y = pos / 5, p3x = pos - 5 * (pos / 5);

        uint32x4 Bc[2], Bn[2];
#pragma unroll
        for (int j = 0; j < 2; ++j) Bc[j] = pk3v[((ntp * 2 + j) << 6) + lane];

        for (int tap = 0; tap < 9; ++tap) {
            const int dy = tap / 3, dx = tap - 3 * (tap / 3);
            int ay = p3y + dy - 1, ax = p3x + dx - 1;
            int r = ((unsigned)ay < 5u && (unsigned)ax < 5u) ? ay * 5 + ax : 25;
            int ao = 25600 + (r << 4) + kgbase2;
#pragma unroll
            for (int cs = 0; cs < 4; ++cs) {
                int nk = tap * 4 + cs + 1;
                if (nk < 36) {
#pragma unroll
                    for (int j = 0; j < 2; ++j)
                        Bn[j] = pk3v[(((nk << 2) + ntp * 2 + j) << 6) + lane];
                }
                bf16x8 A = *(const bf16x8*)(const void*)(s_u + cs * 1664 + ao);
#pragma unroll
                for (int j = 0; j < 2; ++j)
                    c3[j] = __builtin_amdgcn_mfma_f32_16x16x32_bf16(
                        A, __builtin_bit_cast(bf16x8, Bc[j]), c3[j], 0, 0, 0);
#pragma unroll
                for (int j = 0; j < 2; ++j) Bc[j] = Bn[j];
            }
        }
        // epilogue: relu, store bf16 act3T (k-major, base 0)
#pragma unroll
        for (int j = 0; j < 2; ++j) {
            int co = ntp * 32 + j * 16 + l15;
            int kb = co >> 3, cb = (co & 7) * 2;
#pragma unroll
            for (int rr = 0; rr < 4; ++rr) {
                int p = mt * 16 + kg * 4 + rr;
                if (p < 25)
                    *(__bf16*)(s_u + kb * 416 + p * 16 + cb) =
                        (__bf16)fmaxf(c3[j][rr], 0.f);
            }
        }
    }
    __syncthreads();

    // ---------------- P4: conv4 (64->64) MFMA, M=16, N=64, K=576 + pool ----------------
    {
        const int nt = w;
        const uint32x4* pk4v = (const uint32x4*)((const __hip_bfloat16*)wsb + 221184);
        float bj = b4[nt * 16 + l15];
        f32x4 c4 = (f32x4){bj, bj, bj, bj};
        int py = l15 >> 2, px = l15 & 3;

        uint32x4 Bc = pk4v[(nt << 6) + lane], Bn;
        for (int ks = 0; ks < 18; ++ks) {
            if (ks < 17) Bn = pk4v[((((ks + 1) << 2) + nt) << 6) + lane];
            int half = ks & 1, tap = ks >> 1;
            int dy = tap / 3, dx = tap - 3 * (tap / 3);
            int ay = py + dy - 1, ax = px + dx - 1;
            int r = ((unsigned)ay < 5u && (unsigned)ax < 5u) ? ay * 5 + ax : 25;
            bf16x8 A = *(const bf16x8*)(const void*)(
                s_u + (half * 4 + kg) * 416 + (r << 4));
            c4 = __builtin_amdgcn_mfma_f32_16x16x32_bf16(
                A, __builtin_bit_cast(bf16x8, Bc), c4, 0, 0, 0);
            Bc = Bn;
        }
#pragma unroll
        for (int rr = 0; rr < 4; ++rr) {
            int p = kg * 4 + rr;
            int cell = ((p >> 2) >> 1) * 2 + ((p & 3) >> 1);
            float rv = fmaxf(c4[rr], 0.f);
            atomicMax((int*)&s_pool4[cell * 64 + nt * 16 + l15], __float_as_int(rv));
        }
    }
    __syncthreads();

    // ---------------- P5: mean + dense1 ----------------
    if (t < 64) {
        float f = 0.25f * (s_pool4[t] + s_pool4[64 + t] + s_pool4[128 + t] + s_pool4[192 + t]);
        s_feat[t] = f;
    }
    __syncthreads();
    if (t < 32) {
        float h = bd1[t];
        for (int i = 0; i < 64; ++i) h = fmaf(s_feat[i], wd1[i * 32 + t], h);
        s_h[t] = fmaxf(h, 0.f);
    }
    __syncthreads();

    // ---------------- P6: dense2 + sigmoid + bezier + round + sort + dedup ----------------
    if (t == 0) {
        float v[4];
#pragma unroll
        for (int o = 0; o < 4; ++o) {
            float vv = bd2[o];
            for (int i = 0; i < 32; ++i) vv = fmaf(s_h[i], wd2[i * 4 + o], vv);
            v[o] = 1.f / (1.f + expf(-vv));
        }
        float px[5], py[5], pp[5];
#pragma unroll
        for (int k = 0; k < 5; ++k) {
            float tk = 0.25f * (float)k;
            float gx = ((1.f - tk) * v[0] + tk * v[2]) * 10.f;
            float gy = ((1.f - tk) * v[1] + tk * v[3]) * 10.f;
            px[k] = rintf(gx);
            py[k] = rintf(gy);
            pp[k] = px[k] * 10.f + py[k];
        }
#pragma unroll
        for (int pass = 0; pass < 4; ++pass)
#pragma unroll
            for (int i = 0; i < 4 - pass; ++i) {
                bool sw = pp[i] > pp[i + 1];
                float a, b;
                a = pp[i]; b = pp[i + 1]; pp[i] = sw ? b : a; pp[i + 1] = sw ? a : b;
                a = px[i]; b = px[i + 1]; px[i] = sw ? b : a; px[i + 1] = sw ? a : b;
                a = py[i]; b = py[i + 1]; py[i] = sw ? b : a; py[i + 1] = sw ? a : b;
            }
        float* op = out + img * 10;
#pragma unroll
        for (int i = 0; i < 5; ++i) { op[2 * i] = -1.f; op[2 * i + 1] = -1.f; }
        int k2 = 0;
#pragma unroll
        for (int i = 0; i < 5; ++i) {
            bool keep;
            if (i == 0) keep = true;
            else keep = (fabsf(px[i] - px[i - 1]) + fabsf(py[i] - py[i - 1])) != 0.f;
            if (keep) {
                op[2 * k2] = px[i];
                op[2 * k2 + 1] = py[i];
                ++k2;
            }
        }
    }
}

extern "C" void kernel_launch(void* const* d_in, const int* in_sizes, int n_in,
                              void* d_out, int out_size, void* d_ws, size_t ws_size,
                              hipStream_t stream) {
    const float* data = (const float*)d_in[0];
    const float* w1  = (const float*)d_in[1];
    const float* b1  = (const float*)d_in[2];
    const float* w2  = (const float*)d_in[3];
    const float* b2  = (const float*)d_in[4];
    const float* w3  = (const float*)d_in[5];
    const float* b3  = (const float*)d_in[6];
    const float* w4  = (const float*)d_in[7];
    const float* b4  = (const float*)d_in[8];
    const float* wd1 = (const float*)d_in[9];
    const float* bd1 = (const float*)d_in[10];
    const float* wd2 = (const float*)d_in[11];
    const float* bd2 = (const float*)d_in[12];
    float* out = (float*)d_out;
    __hip_bfloat16* wsb = (__hip_bfloat16*)d_ws;

    repack_w<<<1024, 256, 0, stream>>>(w1, w2, w3, w4, wsb);

    int nimg = in_sizes[0] / 100;
    img2svg_fused<<<nimg, NT, 0, stream>>>(data, b1, b2, b3, b4,
                                           wd1, bd1, wd2, bd2, wsb, out);
}